// Round 15
// baseline (73.159 us; speedup 1.0000x reference)
//
#include <hip/hip_runtime.h>
#include <hip/hip_bf16.h>
#include <cstdint>
#include <cstddef>

typedef __bf16 bf16_t;
typedef bf16_t bf16x8 __attribute__((ext_vector_type(8)));
typedef float f32x4 __attribute__((ext_vector_type(4)));
typedef float f32x16 __attribute__((ext_vector_type(16)));
typedef unsigned short u16;
typedef u16 u16x8 __attribute__((ext_vector_type(8)));

#define S_LEN 2048
#define NB 2
#define NH 8
#define DHD 64
#define DM 512

static __device__ __forceinline__ u16 bfbits(float f) {
  union { __bf16 h; u16 u; } c; c.h = (__bf16)f; return c.u;
}
static __device__ __forceinline__ float bits2f(u16 b) {
  union { u16 u; __bf16 h; } c; c.u = b; return (float)c.h;
}
static __device__ __forceinline__ uint32_t pkbf(float a, float b) {
  union { __bf16 h[2]; uint32_t u; } c;
  c.h[0] = (__bf16)a; c.h[1] = (__bf16)b;
  return c.u;
}
// async global->LDS, 16B per lane; LDS dest is wave-uniform base + lane*16
static __device__ __forceinline__ void gload16(const void* g, void* l) {
  __builtin_amdgcn_global_load_lds(
      (const __attribute__((address_space(1))) uint32_t*)g,
      (__attribute__((address_space(3))) uint32_t*)l, 16, 0, 0);
}

// slots for split-K partials: per bh, qb 5..15, 4 waves, nc chunks
static __device__ __forceinline__ int slot_of(int bh, int t32, int chunk) {
  int qb = t32 >> 2;
  int nc = (2 * (qb + 1) + 9) / 10;
  int off;
  if (qb < 10) off = (qb - 5) * 8;
  else if (qb < 15) off = 40 + (qb - 10) * 12;
  else off = 100;
  return bh * 116 + off + (t32 & 3) * nc + chunk;
}

// ---------------------------------------------------------------------------
// Projection GEMM, W-STATIONARY / BARRIER-FREE main loop.
// P = relu(X @ W^T + b); Q pre-scaled by 0.125*log2(e).
// Block owns a 64-col W-quadrant in LDS (loaded once, XOR-swizzled,
// conflict-free reads) and 256 m-rows (64 per wave). X streamed directly
// global->register (fp32, 16x128B coalesced segments per frag), cvt to bf16
// in flight. NO __syncthreads in the k-loop -> waves free-run, compiler
// pipelines loads across the fully-unrolled 16 steps.
// Grid 384 = 8 xcd * 6 mgrp * 8 nq; 2 blocks/CU (64 KB LDS).
// ---------------------------------------------------------------------------
__launch_bounds__(256, 2)
__global__ void proj_kernel(const float* __restrict__ Xq, const float* __restrict__ Xk,
                            const float* __restrict__ Xv, const float* __restrict__ W,
                            const float* __restrict__ bias,
                            u16* __restrict__ Qw, u16* __restrict__ Kw,
                            u16* __restrict__ Vt64) {
  __shared__ __align__(16) u16 POOL[32768];   // 64 KB: W-quadrant, then epilogue reuse
  const int bid = blockIdx.x;
  const int xcd = bid & 7;
  const int u = bid >> 3;               // 0..47
  const int nq = u & 7;                 // n-quadrant == head
  const int mgrp = xcd * 6 + (u >> 3);  // 0..47
  const int mg = mgrp * 256;
  const int z = mg >> 12;               // 0..2
  const int m_in = mg & 4095;
  const int b = m_in >> 11;
  const int s0m = m_in & (S_LEN - 1);
  const size_t bhh = (size_t)(b * NH + nq);

  const int t = threadIdx.x;
  const int lane = t & 63;
  const int wid = t >> 6;
  const int fr = lane & 15, fg = lane >> 4;

  // ---- one-time W-quadrant load: 64 rows x 512 cols fp32 -> bf16, swizzled
  {
    const float* Wq = W + (size_t)(nq * 64) * DM;
    const int wrow = t >> 2;            // 0..63
    const int cbase = (t & 3) << 4;     // chunk (8 cols) base
    #pragma unroll 4
    for (int j = 0; j < 16; ++j) {
      int c = cbase + j;                // 0..63
      const float* p = Wq + (size_t)wrow * DM + c * 8;
      float4 lo = *(const float4*)p, hi = *(const float4*)(p + 4);
      u16x8 rr;
      rr[0]=bfbits(lo.x); rr[1]=bfbits(lo.y); rr[2]=bfbits(lo.z); rr[3]=bfbits(lo.w);
      rr[4]=bfbits(hi.x); rr[5]=bfbits(hi.y); rr[6]=bfbits(hi.z); rr[7]=bfbits(hi.w);
      *(u16x8*)&POOL[wrow * 512 + ((c ^ (wrow & 15)) << 3)] = rr;
    }
  }
  __syncthreads();                      // the ONLY barrier before the epilogue

  // ---- barrier-free k-loop: per wave 64 m-rows x 64 n-cols
  const float* __restrict__ Xz = ((z == 0) ? Xq : (z == 1) ? Xk : Xv) + (size_t)m_in * DM;
  const int w64 = wid * 64;
  const float* pA[4];
  #pragma unroll
  for (int mi = 0; mi < 4; ++mi)
    pA[mi] = Xz + (size_t)(w64 + mi * 16 + fr) * DM + fg * 8;

  f32x4 acc[4][4] = {};

  #pragma unroll
  for (int kk = 0; kk < 16; ++kk) {
    const int k0 = kk * 32;
    bf16x8 af[4];
    #pragma unroll
    for (int mi = 0; mi < 4; ++mi) {
      float4 lo = *(const float4*)(pA[mi] + k0);
      float4 hi = *(const float4*)(pA[mi] + k0 + 4);
      union { u16x8 s; bf16x8 v; } f;
      f.s[0]=bfbits(lo.x); f.s[1]=bfbits(lo.y); f.s[2]=bfbits(lo.z); f.s[3]=bfbits(lo.w);
      f.s[4]=bfbits(hi.x); f.s[5]=bfbits(hi.y); f.s[6]=bfbits(hi.z); f.s[7]=bfbits(hi.w);
      af[mi] = f.v;
    }
    bf16x8 bfr[4];
    #pragma unroll
    for (int ni = 0; ni < 4; ++ni) {
      int r = ni * 16 + fr;
      int c = kk * 4 + fg;
      bfr[ni] = *(const bf16x8*)&POOL[r * 512 + ((c ^ (r & 15)) << 3)];
    }
    __builtin_amdgcn_s_setprio(1);
    #pragma unroll
    for (int mi = 0; mi < 4; ++mi)
      #pragma unroll
      for (int ni = 0; ni < 4; ++ni)
        acc[mi][ni] = __builtin_amdgcn_mfma_f32_16x16x32_bf16(af[mi], bfr[ni], acc[mi][ni], 0, 0, 0);
    __builtin_amdgcn_s_setprio(0);
  }

  // ---- epilogue: bias+ReLU, LDS re-layout, coalesced stores
  const float QSCALE = 0.125f * 1.44269504089f;
  __syncthreads();                      // W region dead; safe to overwrite

  if (z == 2) {
    // stage C^T[e][m] (stride 264); rows -> Vt64[bh][sb][e][s%64]
    #pragma unroll
    for (int mi = 0; mi < 4; ++mi) {
      #pragma unroll
      for (int ni = 0; ni < 4; ++ni) {
        int e = ni * 16 + fr;
        int m = w64 + mi * 16 + fg * 4;
        float bv = bias[nq * 64 + e];
        float v0 = fmaxf(acc[mi][ni][0] + bv, 0.f);
        float v1 = fmaxf(acc[mi][ni][1] + bv, 0.f);
        float v2 = fmaxf(acc[mi][ni][2] + bv, 0.f);
        float v3 = fmaxf(acc[mi][ni][3] + bv, 0.f);
        uint2 w; w.x = pkbf(v0, v1); w.y = pkbf(v2, v3);
        *(uint2*)&POOL[e * 264 + m] = w;
      }
    }
    __syncthreads();
    const int e = t >> 2, seg = t & 3;
    const int sb = (s0m >> 6) + seg;
    u16* dst = Vt64 + (((size_t)bhh * 32 + sb) * 64 + e) * 64;
    #pragma unroll
    for (int i = 0; i < 8; ++i)         // FIX: full 64-u16 row (was i<4 = half)
      *(uint4*)(dst + i * 8) = *(const uint4*)&POOL[e * 264 + seg * 64 + i * 8];
  } else {
    // stage C[m][e] (stride 72); rows -> Qw/Kw[bh][s][dh]
    #pragma unroll
    for (int mi = 0; mi < 4; ++mi) {
      #pragma unroll
      for (int ni = 0; ni < 4; ++ni) {
        int e = ni * 16 + fr;
        float bv = bias[nq * 64 + e];
        #pragma unroll
        for (int r = 0; r < 4; ++r) {
          float v = acc[mi][ni][r] + bv;
          if (z == 0) v *= QSCALE;
          v = fmaxf(v, 0.f);
          POOL[(w64 + mi * 16 + fg * 4 + r) * 72 + e] = bfbits(v);
        }
      }
    }
    __syncthreads();
    u16* dst = ((z == 0) ? Qw : Kw) + (bhh * S_LEN + s0m + t) * DHD;
    #pragma unroll
    for (int i = 0; i < 8; ++i)
      *(uint4*)(dst + i * 8) = *(const uint4*)&POOL[t * 72 + i * 8];
  }
}

// longest-first block table: (qb, chunk) for the 34 blocks per bh
static __device__ const uint8_t QBT[34] = {4,5,6,7,8,9,9,10,10,11,11,12,12,13,13,14,14,14,15,15,15,
                                           3,8,13, 2,7,12, 1,6,11, 0,5,10,15};
static __device__ const uint8_t CKT[34] = {0,0,0,0,0,0,1,0,1,0,1,0,1,0,1,0,1,2,0,1,2,
                                           0,1,2, 0,1,2, 0,1,2, 0,1,2,3};

// ---------------------------------------------------------------------------
// Flash attention (R9/R13 form, unchanged): 4 waves/block, double-buffered
// 64-row K/V LDS tiles via global_load_lds; unnormalized p=exp2(s).
// ---------------------------------------------------------------------------
__launch_bounds__(256, 3)
__global__ void attn_kernel(const u16* __restrict__ Qw, const u16* __restrict__ Kw,
                            const u16* __restrict__ Vt64, u16* __restrict__ Opart,
                            float* __restrict__ lbuf, float* __restrict__ out) {
  __shared__ u16 KLDS[2][4096];
  __shared__ u16 VLDS[2][4096];
  const int t = threadIdx.x;
  const int lane = t & 63;
  const int wid = t >> 6;
  const int lam = lane & 31;
  const int hi = lane >> 5;
  const int h8 = hi << 3, h4 = hi << 2;
  const int bid = blockIdx.x;
  const int bh = bid & 15;              // xcd = bid&7
  const int u = bid >> 4;               // 0..33
  const int qb = QBT[u], chunk = CKT[u];
  const int steps_total = (qb + 1) * 2;
  const int sc0 = chunk * 10;
  const int sc1e = sc0 + 10;
  const int sc1 = (sc1e < steps_total) ? sc1e : steps_total;
  const int t32 = qb * 4 + wid;
  const int q0 = qb * 128 + wid * 32;

  const u16* __restrict__ Qh = Qw + (size_t)bh * S_LEN * DHD;
  const u16* __restrict__ Kh = Kw + (size_t)bh * S_LEN * DHD;
  const u16* __restrict__ V64 = Vt64 + (size_t)bh * 32 * 64 * 64;

  bf16x8 qf[4];
  #pragma unroll
  for (int c = 0; c < 4; ++c)
    qf[c] = *(const bf16x8*)(Qh + (size_t)(q0 + lam) * DHD + c*16 + h8);

  const int lrow = lane >> 3;           // 0..7 within chunk
  const int lblk = lane & 7;
  auto stage = [&](int bf, int s) {
    #pragma unroll
    for (int i = 0; i < 2; ++i) {       // K,V: 8 chunks of 1KB each, 2 per wave
      int c = wid * 2 + i;
      int r = c * 8 + lrow;             // 0..63
      int sw = (lblk ^ (r & 7)) << 3;   // XOR-pre-swizzled source block (u16)
      gload16(Kh + (size_t)(s * 64 + r) * 64 + sw, &KLDS[bf][c * 512]);
      gload16(V64 + ((size_t)s * 64 + r) * 64 + sw, &VLDS[bf][c * 512]);
    }
  };

  f32x16 o0 = {}, o1 = {};
  float lsum = 0.f;

  auto softpack = [&](const f32x16& sc, bool msk, bf16x8& pb0v, bf16x8& pb1v) {
    float p[16];
    #pragma unroll
    for (int r = 0; r < 16; ++r) {
      float ev = __builtin_amdgcn_exp2f(sc[r]);
      int kc = (r & 3) + ((r >> 2) << 3) + h4;
      if (msk && kc > lam) ev = 0.f;
      p[r] = ev;
      lsum += ev;
    }
    uint32_t X0 = pkbf(p[0], p[1]),  X1 = pkbf(p[2], p[3]);
    uint32_t X2 = pkbf(p[4], p[5]),  X3 = pkbf(p[6], p[7]);
    uint32_t X4 = pkbf(p[8], p[9]),  X5 = pkbf(p[10], p[11]);
    uint32_t X6 = pkbf(p[12], p[13]), X7 = pkbf(p[14], p[15]);
    asm("v_permlane32_swap_b32 %0, %1" : "+v"(X0), "+v"(X2));
    asm("v_permlane32_swap_b32 %0, %1" : "+v"(X1), "+v"(X3));
    asm("v_permlane32_swap_b32 %0, %1" : "+v"(X4), "+v"(X6));
    asm("v_permlane32_swap_b32 %0, %1" : "+v"(X5), "+v"(X7));
    union U8 { uint32_t u[4]; bf16x8 v; };
    U8 a, bU;
    a.u[0] = X0; a.u[1] = X1; a.u[2] = X2; a.u[3] = X3;
    bU.u[0] = X4; bU.u[1] = X5; bU.u[2] = X6; bU.u[3] = X7;
    pb0v = a.v; pb1v = bU.v;
  };

  stage(0, sc0);
  int cb = 0;
  for (int s = sc0; s < sc1; ++s) {
    __syncthreads();                    // drains prior stage (compiler vmcnt)
    if (s + 1 < sc1) stage(cb ^ 1, s + 1);
    const int d2 = t32 - 2 * s;         // A computes if >=0 (diag ==0); B if >=1 (diag ==1)
    bf16x8 a0, a1, b0v, b1v;
    f32x16 sA = {}, sB = {};
    if (d2 >= 0) {
      bf16x8 kA[4];
      #pragma unroll
      for (int c = 0; c < 4; ++c) {
        int r = lam, e = ((2*c + hi) ^ (r & 7)) * 8;
        kA[c] = *(const bf16x8*)&KLDS[cb][r*64 + e];
      }
      __builtin_amdgcn_s_setprio(1);
      #pragma unroll
      for (int c = 0; c < 4; ++c)
        sA = __builtin_amdgcn_mfma_f32_32x32x16_bf16(kA[c], qf[c], sA, 0, 0, 0);
      __builtin_amdgcn_s_setprio(0);
    }
    if (d2 >= 1) {
      bf16x8 kB[4];
      #pragma unroll
      for (int c = 0; c < 4; ++c) {
        int r = 32 + lam, e = ((2*c + hi) ^ (r & 7)) * 8;
        kB[c] = *(const bf16x8*)&KLDS[cb][r*64 + e];
      }
      __builtin_amdgcn_s_setprio(1);
      #pragma unroll
      for (int c = 0; c < 4; ++c)
        sB = __builtin_amdgcn_mfma_f32_32x32x16_bf16(kB[c], qf[c], sB, 0, 0, 0);
      __builtin_amdgcn_s_setprio(0);
    }
    if (d2 >= 0) softpack(sA, d2 == 0, a0, a1);
    if (d2 >= 1) softpack(sB, d2 == 1, b0v, b1v);
    if (d2 >= 0) {
      bf16x8 v0[2], v1[2];
      #pragma unroll
      for (int c2 = 0; c2 < 2; ++c2) {
        int r0 = lam,      e0 = ((2*c2 + hi) ^ (r0 & 7)) * 8;
        int r1 = 32 + lam, e1 = ((2*c2 + hi) ^ (r1 & 7)) * 8;
        v0[c2] = *(const bf16x8*)&VLDS[cb][r0*64 + e0];
        v1[c2] = *(const bf16x8*)&VLDS[cb][r1*64 + e1];
      }
      __builtin_amdgcn_s_setprio(1);
      o0 = __builtin_amdgcn_mfma_f32_32x32x16_bf16(v0[0], a0, o0, 0, 0, 0);
      o0 = __builtin_amdgcn_mfma_f32_32x32x16_bf16(v0[1], a1, o0, 0, 0, 0);
      o1 = __builtin_amdgcn_mfma_f32_32x32x16_bf16(v1[0], a0, o1, 0, 0, 0);
      o1 = __builtin_amdgcn_mfma_f32_32x32x16_bf16(v1[1], a1, o1, 0, 0, 0);
      __builtin_amdgcn_s_setprio(0);
    }
    if (d2 >= 1) {
      bf16x8 v0[2], v1[2];
      #pragma unroll
      for (int c2 = 0; c2 < 2; ++c2) {
        int r0 = lam,      e0 = ((4 + 2*c2 + hi) ^ (r0 & 7)) * 8;
        int r1 = 32 + lam, e1 = ((4 + 2*c2 + hi) ^ (r1 & 7)) * 8;
        v0[c2] = *(const bf16x8*)&VLDS[cb][r0*64 + e0];
        v1[c2] = *(const bf16x8*)&VLDS[cb][r1*64 + e1];
      }
      __builtin_amdgcn_s_setprio(1);
      o0 = __builtin_amdgcn_mfma_f32_32x32x16_bf16(v0[0], b0v, o0, 0, 0, 0);
      o0 = __builtin_amdgcn_mfma_f32_32x32x16_bf16(v0[1], b1v, o0, 0, 0, 0);
      o1 = __builtin_amdgcn_mfma_f32_32x32x16_bf16(v1[0], b0v, o1, 0, 0, 0);
      o1 = __builtin_amdgcn_mfma_f32_32x32x16_bf16(v1[1], b1v, o1, 0, 0, 0);
      __builtin_amdgcn_s_setprio(0);
    }
    cb ^= 1;
  }

  float l = lsum + __shfl_xor(lsum, 32);

  if (qb <= 4) {
    const int b = bh >> 3, hh = bh & 7;
    const float inv = 1.0f / l;
    float* orow = out + (((size_t)(hh * NB + b)) * S_LEN + (q0 + lam)) * DHD;
    #pragma unroll
    for (int r = 0; r < 16; ++r) {
      int d = (r & 3) + ((r >> 2) << 3) + h4;
      orow[d] = o0[r] * inv;
      orow[d + 32] = o1[r] * inv;
    }
  } else {
    const int slot = slot_of(bh, t32, chunk);
    uint32_t w[16] __attribute__((aligned(16)));
    #pragma unroll
    for (int m = 0; m < 8; ++m) {
      w[m]     = pkbf(o0[2*m], o0[2*m+1]);
      w[8 + m] = pkbf(o1[2*m], o1[2*m+1]);
    }
    u16* op = Opart + (size_t)slot * 2048 + (size_t)lane * 32;
    #pragma unroll
    for (int i = 0; i < 4; ++i)
      *(uint4*)(op + i*8) = *(const uint4*)&w[i*4];
    if (lane < 32) lbuf[slot * 32 + lane] = l;
  }
}

// ---------------------------------------------------------------------------
// Combine split-K partials for tiles with qb>=5 (t32 20..63): plain sums.
// ---------------------------------------------------------------------------
__launch_bounds__(256)
__global__ void reduce_kernel(const u16* __restrict__ Opart,
                              const float* __restrict__ lbuf,
                              float* __restrict__ out) {
  const int t = threadIdx.x;
  const int unit = blockIdx.x * 4 + (t >> 6);   // 0..703
  const int bh = unit & 15;
  const int ti = 20 + (unit >> 4);              // t32 20..63
  const int qb = ti >> 2;
  const int nc = (2 * (qb + 1) + 9) / 10;       // 2..4
  const int lane = t & 63;
  const int lam = lane & 31;
  const int h4 = (lane >> 5) << 2;
  const int slot0 = slot_of(bh, ti, 0);

  float O[32];
  #pragma unroll
  for (int i = 0; i < 32; ++i) O[i] = 0.f;
  float L = 0.f;

  for (int c = 0; c < nc; ++c) {
    const u16* op = Opart + (size_t)(slot0 + c) * 2048 + (size_t)lane * 32;
    L += lbuf[(slot0 + c) * 32 + lam];
    #pragma unroll
    for (int i = 0; i < 4; ++i) {
      uint4 v = *(const uint4*)(op + i*8);
      uint32_t a[4] = {v.x, v.y, v.z, v.w};
      #pragma unroll
      for (int jj = 0; jj < 4; ++jj) {
        O[i*8 + 2*jj]     += bits2f((u16)(a[jj] & 0xFFFFu));
        O[i*8 + 2*jj + 1] += bits2f((u16)(a[jj] >> 16));
      }
    }
  }

  const int b = bh >> 3, hh = bh & 7;
  const float inv = 1.0f / L;
  float* orow = out + (((size_t)(hh * NB + b)) * S_LEN + (ti*32 + lam)) * DHD;
  #pragma unroll
  for (int r = 0; r < 16; ++r) {
    int d = (r & 3) + ((r >> 2) << 3) + h4;
    orow[d] = O[r] * inv;
    orow[d + 32] = O[16 + r] * inv;
  }
}

extern "C" void kernel_launch(void* const* d_in, const int* in_sizes, int n_in,
                              void* d_out, int out_size, void* d_ws, size_t ws_size,
                              hipStream_t stream) {
  const float* q = (const float*)d_in[0];
  const float* k = (const float*)d_in[1];
  const float* v = (const float*)d_in[2];
  const float* W = (const float*)d_in[3];
  const float* b = (const float*)d_in[4];

  const size_t elems = (size_t)NB * NH * S_LEN * DHD;  // 2,097,152
  u16* Qw = (u16*)d_ws;
  u16* Kw = Qw + elems;
  u16* Vt64 = Kw + elems;
  u16* Opart = Vt64 + elems;                           // 1856 slots * 4 KiB = 7.25 MiB
  float* lbuf = (float*)(Opart + (size_t)1856 * 2048); // 232 KiB

  proj_kernel<<<dim3(384), dim3(256), 0, stream>>>(q, k, v, W, b, Qw, Kw, Vt64);

  attn_kernel<<<dim3(544), dim3(256), 0, stream>>>(Qw, Kw, Vt64, Opart, lbuf, (float*)d_out);

  reduce_kernel<<<dim3(176), dim3(256), 0, stream>>>(Opart, lbuf, (float*)d_out);
}

// Round 16
// 55.631 us; speedup vs baseline: 1.3151x; 1.3151x over previous
//
#include <hip/hip_runtime.h>
#include <hip/hip_bf16.h>
#include <cstdint>
#include <cstddef>

typedef __bf16 bf16_t;
typedef bf16_t bf16x8 __attribute__((ext_vector_type(8)));
typedef float f32x4 __attribute__((ext_vector_type(4)));
typedef float f32x16 __attribute__((ext_vector_type(16)));
typedef unsigned short u16;
typedef u16 u16x8 __attribute__((ext_vector_type(8)));

#define S_LEN 2048
#define NB 2
#define NH 8
#define DHD 64
#define DM 512

static __device__ __forceinline__ u16 bfbits(float f) {
  union { __bf16 h; u16 u; } c; c.h = (__bf16)f; return c.u;
}
static __device__ __forceinline__ float bits2f(u16 b) {
  union { u16 u; __bf16 h; } c; c.u = b; return (float)c.h;
}
static __device__ __forceinline__ uint32_t pkbf(float a, float b) {
  union { __bf16 h[2]; uint32_t u; } c;
  c.h[0] = (__bf16)a; c.h[1] = (__bf16)b;
  return c.u;
}
// async global->LDS, 16B per lane; LDS dest is wave-uniform base + lane*16
static __device__ __forceinline__ void gload16(const void* g, void* l) {
  __builtin_amdgcn_global_load_lds(
      (const __attribute__((address_space(1))) uint32_t*)g,
      (__attribute__((address_space(3))) uint32_t*)l, 16, 0, 0);
}

// slots for split-K partials: per bh, qb 5..15, 4 waves, nc chunks
static __device__ __forceinline__ int slot_of(int bh, int t32, int chunk) {
  int qb = t32 >> 2;
  int nc = (2 * (qb + 1) + 9) / 10;
  int off;
  if (qb < 10) off = (qb - 5) * 8;
  else if (qb < 15) off = 40 + (qb - 10) * 12;
  else off = 100;
  return bh * 116 + off + (t32 & 3) * nc + chunk;
}

// ---------------------------------------------------------------------------
// fp32 -> bf16 convert pass (BW-bound, ~39 MB). z picks {q,k,v,W}.
// ---------------------------------------------------------------------------
__launch_bounds__(256)
__global__ void cvt_kernel(const float* __restrict__ q, const float* __restrict__ k,
                           const float* __restrict__ v, const float* __restrict__ W,
                           u16* __restrict__ dst) {
  const int z = blockIdx.y;
  if (z == 3 && blockIdx.x >= 128) return;
  const float* __restrict__ src = (z == 0) ? q : (z == 1) ? k : (z == 2) ? v : W;
  u16* __restrict__ d = dst + (size_t)z * 2097152;
  size_t i = ((size_t)blockIdx.x * 256 + threadIdx.x) * 8;
  float4 a = *reinterpret_cast<const float4*>(src + i);
  float4 b = *reinterpret_cast<const float4*>(src + i + 4);
  u16x8 r;
  r[0] = bfbits(a.x); r[1] = bfbits(a.y); r[2] = bfbits(a.z); r[3] = bfbits(a.w);
  r[4] = bfbits(b.x); r[5] = bfbits(b.y); r[6] = bfbits(b.z); r[7] = bfbits(b.w);
  *reinterpret_cast<u16x8*>(d + i) = r;
}

// ---------------------------------------------------------------------------
// Projection GEMM (bf16 in): P = relu(X @ W^T + b); Q pre-scaled 0.125*log2e.
// 128x64 tile, BK=64, 8 steps, plain 2-phase double-buffer (NO sched_barrier,
// NO counted vmcnt). bf16 staged via global_load_lds (XOR-pre-swizzled source,
// linear LDS, XOR read) -> fragment path = pure ds_read_b128, ZERO cvt VALU.
// Grid 768 = 8 xcd * 12 m * 8 n; 48KB LDS -> 3 blocks/CU.
// ---------------------------------------------------------------------------
__launch_bounds__(256, 3)
__global__ void proj_kernel(const u16* __restrict__ Xall, const u16* __restrict__ Wb,
                            const float* __restrict__ bias,
                            u16* __restrict__ Qw, u16* __restrict__ Kw,
                            u16* __restrict__ Vt64) {
  __shared__ __align__(16) u16 BUF[2][12288];  // per buf: A 128x64 @0, B 64x64 @8192
  const int bid = blockIdx.x;
  const int xcd = bid & 7;
  const int u = bid >> 3;               // 0..95
  const int n0 = (u & 7) * 64;
  const int mIdx = u >> 3;              // 0..11
  const int mg = (xcd * 12 + mIdx) * 128;
  const int z = mg >> 12;               // 0..2
  const int m_in = mg & 4095;
  const int b = m_in >> 11;
  const int s0m = m_in & (S_LEN - 1);
  const int hh = n0 >> 6;
  const u16* __restrict__ X = Xall + (size_t)z * 2097152 + (size_t)m_in * DM;

  const int t = threadIdx.x;
  const int lane = t & 63;
  const int wid = t >> 6;
  const int wr = wid >> 1, wc = wid & 1;
  const int fr = lane & 15, fg = lane >> 4;

  f32x4 acc[4][2] = {};

  const int lrow = lane >> 3;           // 0..7 within 8-row chunk
  const int lblk = lane & 7;            // 16B block within 128B row

  auto stage = [&](int bf, int k0) {
    #pragma unroll
    for (int i = 0; i < 4; ++i) {       // A: 16 chunks of 1KB (8 rows x 64 bf16), 4/wave
      int c = wid * 4 + i;
      int r = c * 8 + lrow;
      gload16(X + (size_t)r * DM + k0 + ((lblk ^ (r & 7)) << 3), &BUF[bf][c * 512]);
    }
    #pragma unroll
    for (int i = 0; i < 2; ++i) {       // B: 8 chunks, 2/wave
      int c = wid * 2 + i;
      int r = c * 8 + lrow;
      gload16(Wb + (size_t)(n0 + r) * DM + k0 + ((lblk ^ (r & 7)) << 3),
              &BUF[bf][8192 + c * 512]);
    }
  };

  stage(0, 0);
  int cb = 0;
  for (int i = 0; i < 8; ++i) {
    __syncthreads();                    // drains prior stage (compiler vmcnt)
    if (i < 7) stage(cb ^ 1, (i + 1) * 64);
    #pragma unroll
    for (int ks = 0; ks < 2; ++ks) {
      bf16x8 af[4], bfr[2];
      #pragma unroll
      for (int m2 = 0; m2 < 4; ++m2) {
        int r = wr*64 + m2*16 + fr;
        int e = ks*4 + fg;
        af[m2] = *(const bf16x8*)&BUF[cb][r*64 + ((e ^ (r & 7)) << 3)];
      }
      #pragma unroll
      for (int ni = 0; ni < 2; ++ni) {
        int r = wc*32 + ni*16 + fr;
        int e = ks*4 + fg;
        bfr[ni] = *(const bf16x8*)&BUF[cb][8192 + r*64 + ((e ^ (r & 7)) << 3)];
      }
      __builtin_amdgcn_s_setprio(1);
      #pragma unroll
      for (int m2 = 0; m2 < 4; ++m2)
        #pragma unroll
        for (int ni = 0; ni < 2; ++ni)
          acc[m2][ni] = __builtin_amdgcn_mfma_f32_16x16x32_bf16(af[m2], bfr[ni], acc[m2][ni], 0, 0, 0);
      __builtin_amdgcn_s_setprio(0);
    }
    cb ^= 1;
  }
  __syncthreads();

  const float QSCALE = 0.125f * 1.44269504089f;
  const size_t bhh = (size_t)(b * NH + hh);
  u16* epi = &BUF[0][0];

  if (z == 2) {
    // stage C^T[e][m] (stride 136); coalesced rows -> Vt64[bh][s/64][d][s%64]
    #pragma unroll
    for (int m2 = 0; m2 < 4; ++m2) {
      #pragma unroll
      for (int ni = 0; ni < 2; ++ni) {
        int e = wc*32 + ni*16 + fr;
        int m = wr*64 + m2*16 + fg*4;
        float bv = bias[n0 + e];
        float v0 = fmaxf(acc[m2][ni][0] + bv, 0.f);
        float v1 = fmaxf(acc[m2][ni][1] + bv, 0.f);
        float v2 = fmaxf(acc[m2][ni][2] + bv, 0.f);
        float v3 = fmaxf(acc[m2][ni][3] + bv, 0.f);
        uint2 w; w.x = pkbf(v0, v1); w.y = pkbf(v2, v3);
        *(uint2*)&epi[e*136 + m] = w;
      }
    }
    __syncthreads();
    const int e = t >> 2, mc = (t & 3) * 32;
    const int sb = (s0m >> 6) + (mc >> 6);
    u16* dst = Vt64 + (((size_t)bhh * 32 + sb) * 64 + e) * 64 + (mc & 63);
    #pragma unroll
    for (int i = 0; i < 4; ++i)
      *(uint4*)(dst + i*8) = *(const uint4*)&epi[e*136 + mc + i*8];
  } else {
    // stage C[m][e] (stride 72); coalesced rows -> Qw/Kw[bh][s][dh]
    #pragma unroll
    for (int m2 = 0; m2 < 4; ++m2) {
      #pragma unroll
      for (int ni = 0; ni < 2; ++ni) {
        int e = wc*32 + ni*16 + fr;
        float bv = bias[n0 + e];
        #pragma unroll
        for (int r = 0; r < 4; ++r) {
          float v = acc[m2][ni][r] + bv;
          if (z == 0) v *= QSCALE;
          v = fmaxf(v, 0.f);
          epi[(wr*64 + m2*16 + fg*4 + r)*72 + e] = bfbits(v);
        }
      }
    }
    __syncthreads();
    const int mrow = t >> 1, ec = (t & 1) * 32;
    u16* dst = ((z == 0) ? Qw : Kw) + (bhh * S_LEN + s0m + mrow) * DHD + ec;
    #pragma unroll
    for (int i = 0; i < 4; ++i)
      *(uint4*)(dst + i*8) = *(const uint4*)&epi[mrow*72 + ec + i*8];
  }
}

// longest-first block table: (qb, chunk) for the 34 blocks per bh
static __device__ const uint8_t QBT[34] = {4,5,6,7,8,9,9,10,10,11,11,12,12,13,13,14,14,14,15,15,15,
                                           3,8,13, 2,7,12, 1,6,11, 0,5,10,15};
static __device__ const uint8_t CKT[34] = {0,0,0,0,0,0,1,0,1,0,1,0,1,0,1,0,1,2,0,1,2,
                                           0,1,2, 0,1,2, 0,1,2, 0,1,2,3};

// ---------------------------------------------------------------------------
// Flash attention (R13 form, unchanged): 4 waves/block, double-buffered
// 64-row K/V LDS tiles via global_load_lds; unnormalized p=exp2(s).
// ---------------------------------------------------------------------------
__launch_bounds__(256, 3)
__global__ void attn_kernel(const u16* __restrict__ Qw, const u16* __restrict__ Kw,
                            const u16* __restrict__ Vt64, u16* __restrict__ Opart,
                            float* __restrict__ lbuf, float* __restrict__ out) {
  __shared__ u16 KLDS[2][4096];
  __shared__ u16 VLDS[2][4096];
  const int t = threadIdx.x;
  const int lane = t & 63;
  const int wid = t >> 6;
  const int lam = lane & 31;
  const int hi = lane >> 5;
  const int h8 = hi << 3, h4 = hi << 2;
  const int bid = blockIdx.x;
  const int bh = bid & 15;              // xcd = bid&7
  const int u = bid >> 4;               // 0..33
  const int qb = QBT[u], chunk = CKT[u];
  const int steps_total = (qb + 1) * 2;
  const int sc0 = chunk * 10;
  const int sc1e = sc0 + 10;
  const int sc1 = (sc1e < steps_total) ? sc1e : steps_total;
  const int t32 = qb * 4 + wid;
  const int q0 = qb * 128 + wid * 32;

  const u16* __restrict__ Qh = Qw + (size_t)bh * S_LEN * DHD;
  const u16* __restrict__ Kh = Kw + (size_t)bh * S_LEN * DHD;
  const u16* __restrict__ V64 = Vt64 + (size_t)bh * 32 * 64 * 64;

  bf16x8 qf[4];
  #pragma unroll
  for (int c = 0; c < 4; ++c)
    qf[c] = *(const bf16x8*)(Qh + (size_t)(q0 + lam) * DHD + c*16 + h8);

  const int lrow = lane >> 3;           // 0..7 within chunk
  const int lblk = lane & 7;
  auto stage = [&](int bf, int s) {
    #pragma unroll
    for (int i = 0; i < 2; ++i) {       // K,V: 8 chunks of 1KB each, 2 per wave
      int c = wid * 2 + i;
      int r = c * 8 + lrow;             // 0..63
      int sw = (lblk ^ (r & 7)) << 3;   // XOR-pre-swizzled source block (u16)
      gload16(Kh + (size_t)(s * 64 + r) * 64 + sw, &KLDS[bf][c * 512]);
      gload16(V64 + ((size_t)s * 64 + r) * 64 + sw, &VLDS[bf][c * 512]);
    }
  };

  f32x16 o0 = {}, o1 = {};
  float lsum = 0.f;

  auto softpack = [&](const f32x16& sc, bool msk, bf16x8& pb0v, bf16x8& pb1v) {
    float p[16];
    #pragma unroll
    for (int r = 0; r < 16; ++r) {
      float ev = __builtin_amdgcn_exp2f(sc[r]);
      int kc = (r & 3) + ((r >> 2) << 3) + h4;
      if (msk && kc > lam) ev = 0.f;
      p[r] = ev;
      lsum += ev;
    }
    uint32_t X0 = pkbf(p[0], p[1]),  X1 = pkbf(p[2], p[3]);
    uint32_t X2 = pkbf(p[4], p[5]),  X3 = pkbf(p[6], p[7]);
    uint32_t X4 = pkbf(p[8], p[9]),  X5 = pkbf(p[10], p[11]);
    uint32_t X6 = pkbf(p[12], p[13]), X7 = pkbf(p[14], p[15]);
    asm("v_permlane32_swap_b32 %0, %1" : "+v"(X0), "+v"(X2));
    asm("v_permlane32_swap_b32 %0, %1" : "+v"(X1), "+v"(X3));
    asm("v_permlane32_swap_b32 %0, %1" : "+v"(X4), "+v"(X6));
    asm("v_permlane32_swap_b32 %0, %1" : "+v"(X5), "+v"(X7));
    union U8 { uint32_t u[4]; bf16x8 v; };
    U8 a, bU;
    a.u[0] = X0; a.u[1] = X1; a.u[2] = X2; a.u[3] = X3;
    bU.u[0] = X4; bU.u[1] = X5; bU.u[2] = X6; bU.u[3] = X7;
    pb0v = a.v; pb1v = bU.v;
  };

  stage(0, sc0);
  int cb = 0;
  for (int s = sc0; s < sc1; ++s) {
    __syncthreads();                    // drains prior stage (compiler vmcnt)
    if (s + 1 < sc1) stage(cb ^ 1, s + 1);
    const int d2 = t32 - 2 * s;         // A computes if >=0 (diag ==0); B if >=1 (diag ==1)
    bf16x8 a0, a1, b0v, b1v;
    f32x16 sA = {}, sB = {};
    if (d2 >= 0) {
      bf16x8 kA[4];
      #pragma unroll
      for (int c = 0; c < 4; ++c) {
        int r = lam, e = ((2*c + hi) ^ (r & 7)) * 8;
        kA[c] = *(const bf16x8*)&KLDS[cb][r*64 + e];
      }
      __builtin_amdgcn_s_setprio(1);
      #pragma unroll
      for (int c = 0; c < 4; ++c)
        sA = __builtin_amdgcn_mfma_f32_32x32x16_bf16(kA[c], qf[c], sA, 0, 0, 0);
      __builtin_amdgcn_s_setprio(0);
    }
    if (d2 >= 1) {
      bf16x8 kB[4];
      #pragma unroll
      for (int c = 0; c < 4; ++c) {
        int r = 32 + lam, e = ((2*c + hi) ^ (r & 7)) * 8;
        kB[c] = *(const bf16x8*)&KLDS[cb][r*64 + e];
      }
      __builtin_amdgcn_s_setprio(1);
      #pragma unroll
      for (int c = 0; c < 4; ++c)
        sB = __builtin_amdgcn_mfma_f32_32x32x16_bf16(kB[c], qf[c], sB, 0, 0, 0);
      __builtin_amdgcn_s_setprio(0);
    }
    if (d2 >= 0) softpack(sA, d2 == 0, a0, a1);
    if (d2 >= 1) softpack(sB, d2 == 1, b0v, b1v);
    if (d2 >= 0) {
      bf16x8 v0[2], v1[2];
      #pragma unroll
      for (int c2 = 0; c2 < 2; ++c2) {
        int r0 = lam,      e0 = ((2*c2 + hi) ^ (r0 & 7)) * 8;
        int r1 = 32 + lam, e1 = ((2*c2 + hi) ^ (r1 & 7)) * 8;
        v0[c2] = *(const bf16x8*)&VLDS[cb][r0*64 + e0];
        v1[c2] = *(const bf16x8*)&VLDS[cb][r1*64 + e1];
      }
      __builtin_amdgcn_s_setprio(1);
      o0 = __builtin_amdgcn_mfma_f32_32x32x16_bf16(v0[0], a0, o0, 0, 0, 0);
      o0 = __builtin_amdgcn_mfma_f32_32x32x16_bf16(v0[1], a1, o0, 0, 0, 0);
      o1 = __builtin_amdgcn_mfma_f32_32x32x16_bf16(v1[0], a0, o1, 0, 0, 0);
      o1 = __builtin_amdgcn_mfma_f32_32x32x16_bf16(v1[1], a1, o1, 0, 0, 0);
      __builtin_amdgcn_s_setprio(0);
    }
    if (d2 >= 1) {
      bf16x8 v0[2], v1[2];
      #pragma unroll
      for (int c2 = 0; c2 < 2; ++c2) {
        int r0 = lam,      e0 = ((4 + 2*c2 + hi) ^ (r0 & 7)) * 8;
        int r1 = 32 + lam, e1 = ((4 + 2*c2 + hi) ^ (r1 & 7)) * 8;
        v0[c2] = *(const bf16x8*)&VLDS[cb][r0*64 + e0];
        v1[c2] = *(const bf16x8*)&VLDS[cb][r1*64 + e1];
      }
      __builtin_amdgcn_s_setprio(1);
      o0 = __builtin_amdgcn_mfma_f32_32x32x16_bf16(v0[0], b0v, o0, 0, 0, 0);
      o0 = __builtin_amdgcn_mfma_f32_32x32x16_bf16(v0[1], b1v, o0, 0, 0, 0);
      o1 = __builtin_amdgcn_mfma_f32_32x32x16_bf16(v1[0], b0v, o1, 0, 0, 0);
      o1 = __builtin_amdgcn_mfma_f32_32x32x16_bf16(v1[1], b1v, o1, 0, 0, 0);
      __builtin_amdgcn_s_setprio(0);
    }
    cb ^= 1;
  }

  float l = lsum + __shfl_xor(lsum, 32);

  if (qb <= 4) {
    const int b = bh >> 3, hh = bh & 7;
    const float inv = 1.0f / l;
    float* orow = out + (((size_t)(hh * NB + b)) * S_LEN + (q0 + lam)) * DHD;
    #pragma unroll
    for (int r = 0; r < 16; ++r) {
      int d = (r & 3) + ((r >> 2) << 3) + h4;
      orow[d] = o0[r] * inv;
      orow[d + 32] = o1[r] * inv;
    }
  } else {
    const int slot = slot_of(bh, t32, chunk);
    uint32_t w[16] __attribute__((aligned(16)));
    #pragma unroll
    for (int m = 0; m < 8; ++m) {
      w[m]     = pkbf(o0[2*m], o0[2*m+1]);
      w[8 + m] = pkbf(o1[2*m], o1[2*m+1]);
    }
    u16* op = Opart + (size_t)slot * 2048 + (size_t)lane * 32;
    #pragma unroll
    for (int i = 0; i < 4; ++i)
      *(uint4*)(op + i*8) = *(const uint4*)&w[i*4];
    if (lane < 32) lbuf[slot * 32 + lane] = l;
  }
}

// ---------------------------------------------------------------------------
// Combine split-K partials for tiles with qb>=5 (t32 20..63): plain sums.
// ---------------------------------------------------------------------------
__launch_bounds__(256)
__global__ void reduce_kernel(const u16* __restrict__ Opart,
                              const float* __restrict__ lbuf,
                              float* __restrict__ out) {
  const int t = threadIdx.x;
  const int unit = blockIdx.x * 4 + (t >> 6);   // 0..703
  const int bh = unit & 15;
  const int ti = 20 + (unit >> 4);              // t32 20..63
  const int qb = ti >> 2;
  const int nc = (2 * (qb + 1) + 9) / 10;       // 2..4
  const int lane = t & 63;
  const int lam = lane & 31;
  const int h4 = (lane >> 5) << 2;
  const int slot0 = slot_of(bh, ti, 0);

  float O[32];
  #pragma unroll
  for (int i = 0; i < 32; ++i) O[i] = 0.f;
  float L = 0.f;

  for (int c = 0; c < nc; ++c) {
    const u16* op = Opart + (size_t)(slot0 + c) * 2048 + (size_t)lane * 32;
    L += lbuf[(slot0 + c) * 32 + lam];
    #pragma unroll
    for (int i = 0; i < 4; ++i) {
      uint4 v = *(const uint4*)(op + i*8);
      uint32_t a[4] = {v.x, v.y, v.z, v.w};
      #pragma unroll
      for (int jj = 0; jj < 4; ++jj) {
        O[i*8 + 2*jj]     += bits2f((u16)(a[jj] & 0xFFFFu));
        O[i*8 + 2*jj + 1] += bits2f((u16)(a[jj] >> 16));
      }
    }
  }

  const int b = bh >> 3, hh = bh & 7;
  const float inv = 1.0f / L;
  float* orow = out + (((size_t)(hh * NB + b)) * S_LEN + (ti*32 + lam)) * DHD;
  #pragma unroll
  for (int r = 0; r < 16; ++r) {
    int d = (r & 3) + ((r >> 2) << 3) + h4;
    orow[d] = O[r] * inv;
    orow[d + 32] = O[16 + r] * inv;
  }
}

extern "C" void kernel_launch(void* const* d_in, const int* in_sizes, int n_in,
                              void* d_out, int out_size, void* d_ws, size_t ws_size,
                              hipStream_t stream) {
  const float* q = (const float*)d_in[0];
  const float* k = (const float*)d_in[1];
  const float* v = (const float*)d_in[2];
  const float* W = (const float*)d_in[3];
  const float* b = (const float*)d_in[4];

  const size_t elems = (size_t)NB * NH * S_LEN * DHD;  // 2,097,152
  u16* Qw = (u16*)d_ws;
  u16* Kw = Qw + elems;
  u16* Vt64 = Kw + elems;
  u16* Xb = Vt64 + elems;               // 3*elems (q,k,v) + 262144 (W) bf16 = 12.5 MiB
  u16* Wb = Xb + 3 * elems;
  // Opart overlaps Xb: Xb/Wb consumed by proj before attn writes partials
  u16* Opart = Xb;                      // 1856 slots * 4 KiB = 7.25 MiB < 12.5 MiB
  float* lbuf = (float*)(Wb + 262144);  // 232 KiB

  cvt_kernel<<<dim3(1024, 4), dim3(256), 0, stream>>>(q, k, v, W, Xb);

  proj_kernel<<<dim3(768), dim3(256), 0, stream>>>(Xb, Wb, b, Qw, Kw, Vt64);

  attn_kernel<<<dim3(544), dim3(256), 0, stream>>>(Qw, Kw, Vt64, Opart, lbuf, (float*)d_out);

  reduce_kernel<<<dim3(176), dim3(256), 0, stream>>>(Opart, lbuf, (float*)d_out);
}

// Round 17
// 50.685 us; speedup vs baseline: 1.4434x; 1.0976x over previous
//
#include <hip/hip_runtime.h>
#include <hip/hip_bf16.h>
#include <cstdint>
#include <cstddef>

typedef __bf16 bf16_t;
typedef bf16_t bf16x8 __attribute__((ext_vector_type(8)));
typedef float f32x4 __attribute__((ext_vector_type(4)));
typedef float f32x16 __attribute__((ext_vector_type(16)));
typedef unsigned short u16;
typedef u16 u16x8 __attribute__((ext_vector_type(8)));

#define S_LEN 2048
#define NB 2
#define NH 8
#define DHD 64
#define DM 512
#define SLOTS_PER_BH 192   // 4 waves x sum_{qb>=3} ceil((qb+1)/3)

static __device__ __forceinline__ u16 bfbits(float f) {
  union { __bf16 h; u16 u; } c; c.h = (__bf16)f; return c.u;
}
static __device__ __forceinline__ float bits2f(u16 b) {
  union { u16 u; __bf16 h; } c; c.u = b; return (float)c.h;
}
static __device__ __forceinline__ uint32_t pkbf(float a, float b) {
  union { __bf16 h[2]; uint32_t u; } c;
  c.h[0] = (__bf16)a; c.h[1] = (__bf16)b;
  return c.u;
}
// async global->LDS, 16B per lane; LDS dest is wave-uniform base + lane*16
static __device__ __forceinline__ void gload16(const void* g, void* l) {
  __builtin_amdgcn_global_load_lds(
      (const __attribute__((address_space(1))) uint32_t*)g,
      (__attribute__((address_space(3))) uint32_t*)l, 16, 0, 0);
}

// split-K partial slots (chunk = 6 steps): qb>=3 tiles only.
// off4 = 4-slot-unit offset of qb group; nc = ceil((qb+1)/3) = (qb+3)/3
static __device__ __forceinline__ int slot_of(int bh, int t32, int chunk) {
  int qb = t32 >> 2;
  int nc = (qb + 3) / 3;
  int off4;
  if (qb < 6)       off4 = (qb - 3) * 2;            // qb 3..5: nc=2
  else if (qb < 9)  off4 = 6 + (qb - 6) * 3;        // qb 6..8: nc=3
  else if (qb < 12) off4 = 15 + (qb - 9) * 4;       // qb 9..11: nc=4
  else if (qb < 15) off4 = 27 + (qb - 12) * 5;      // qb 12..14: nc=5
  else              off4 = 42;                      // qb 15: nc=6
  return bh * SLOTS_PER_BH + off4 * 4 + (t32 & 3) * nc + chunk;
}

// ---------------------------------------------------------------------------
// Projection GEMM (R13 verbatim): P = relu(X @ W^T + b); Q scaled 0.125*log2e.
// 128x128 tile, BK=32, 16 steps, 2 LDS bufs; fp32 staged via global_load_lds
// (XOR-pre-swizzled source, linear LDS, XOR read); cvt at fragment build.
// ---------------------------------------------------------------------------
__launch_bounds__(256, 2)
__global__ void proj_kernel(const float* __restrict__ Xq, const float* __restrict__ Xk,
                            const float* __restrict__ Xv, const float* __restrict__ W,
                            const float* __restrict__ bias,
                            u16* __restrict__ Qw, u16* __restrict__ Kw,
                            u16* __restrict__ Vt64) {
  __shared__ __align__(16) float BUF[2][8192];   // per buf: A 128x32 @0, B 128x32 @4096
  const int bid = blockIdx.x;
  const int xcd = bid & 7;
  const int u = bid >> 3;               // 0..47
  const int n0 = (u & 3) * 128;
  const int mIdx = u >> 2;              // 0..11
  const int mg = (xcd * 12 + mIdx) * 128;
  const int z = mg >> 12;               // 0..2
  const int m_in = mg & 4095;
  const int b = m_in >> 11;
  const int s0m = m_in & (S_LEN - 1);
  const int h0 = n0 >> 6;               // first of 2 heads in this n-span
  const float* __restrict__ X = (z == 0) ? Xq : ((z == 1) ? Xk : Xv);
  X += (size_t)m_in * DM;

  const int t = threadIdx.x;
  const int lane = t & 63;
  const int wid = t >> 6;
  const int wr = wid >> 1, wc = wid & 1;
  const int fr = lane & 15, fg = lane >> 4;

  f32x4 acc[4][4] = {};

  const int lrow = lane >> 3;           // 0..7 within chunk
  const int lblk = lane & 7;            // 16B block within 128B row

  auto stage = [&](int bf, int k0) {
    #pragma unroll
    for (int i = 0; i < 4; ++i) {       // A: 16 chunks of 1KB (8 rows), 4/wave
      int c = wid * 4 + i;
      int r = c * 8 + lrow;
      gload16(X + (size_t)r * DM + k0 + ((lblk ^ (r & 7)) << 2), &BUF[bf][c * 256]);
    }
    #pragma unroll
    for (int i = 0; i < 4; ++i) {       // B: 16 chunks, 4/wave
      int c = wid * 4 + i;
      int r = c * 8 + lrow;
      gload16(W + (size_t)(n0 + r) * DM + k0 + ((lblk ^ (r & 7)) << 2),
              &BUF[bf][4096 + c * 256]);
    }
  };

  stage(0, 0);
  int cb = 0;
  for (int i = 0; i < 16; ++i) {
    __syncthreads();                    // drains prior stage (compiler vmcnt)
    if (i < 15) stage(cb ^ 1, (i + 1) * 32);
    const float* Ac = BUF[cb];
    bf16x8 af[4], bfr[4];
    #pragma unroll
    for (int m2 = 0; m2 < 4; ++m2) {
      int r = wr*64 + m2*16 + fr;
      f32x4 lo = *(const f32x4*)&Ac[r*32 + (((2*fg)     ^ (r & 7)) << 2)];
      f32x4 hi = *(const f32x4*)&Ac[r*32 + (((2*fg + 1) ^ (r & 7)) << 2)];
      union { u16x8 s; bf16x8 v; } f;
      f.s[0]=bfbits(lo[0]); f.s[1]=bfbits(lo[1]); f.s[2]=bfbits(lo[2]); f.s[3]=bfbits(lo[3]);
      f.s[4]=bfbits(hi[0]); f.s[5]=bfbits(hi[1]); f.s[6]=bfbits(hi[2]); f.s[7]=bfbits(hi[3]);
      af[m2] = f.v;
    }
    #pragma unroll
    for (int ni = 0; ni < 4; ++ni) {
      int r = wc*64 + ni*16 + fr;
      f32x4 lo = *(const f32x4*)&Ac[4096 + r*32 + (((2*fg)     ^ (r & 7)) << 2)];
      f32x4 hi = *(const f32x4*)&Ac[4096 + r*32 + (((2*fg + 1) ^ (r & 7)) << 2)];
      union { u16x8 s; bf16x8 v; } f;
      f.s[0]=bfbits(lo[0]); f.s[1]=bfbits(lo[1]); f.s[2]=bfbits(lo[2]); f.s[3]=bfbits(lo[3]);
      f.s[4]=bfbits(hi[0]); f.s[5]=bfbits(hi[1]); f.s[6]=bfbits(hi[2]); f.s[7]=bfbits(hi[3]);
      bfr[ni] = f.v;
    }
    __builtin_amdgcn_s_setprio(1);
    #pragma unroll
    for (int m2 = 0; m2 < 4; ++m2)
      #pragma unroll
      for (int ni = 0; ni < 4; ++ni)
        acc[m2][ni] = __builtin_amdgcn_mfma_f32_16x16x32_bf16(af[m2], bfr[ni], acc[m2][ni], 0, 0, 0);
    __builtin_amdgcn_s_setprio(0);
    cb ^= 1;
  }
  __syncthreads();

  const float QSCALE = 0.125f * 1.44269504089f;
  u16* epi = (u16*)&BUF[0][0];          // 128 x 136 u16 = 34 KB, fits 64 KB pool

  if (z == 2) {
    // stage C^T[e][m] (stride 136); coalesced rows -> Vt64[bh][s/64][d][s%64]
    #pragma unroll
    for (int m2 = 0; m2 < 4; ++m2) {
      #pragma unroll
      for (int ni = 0; ni < 4; ++ni) {
        int e = wc*64 + ni*16 + fr;
        int m = wr*64 + m2*16 + fg*4;
        float bv = bias[n0 + e];
        float v0 = fmaxf(acc[m2][ni][0] + bv, 0.f);
        float v1 = fmaxf(acc[m2][ni][1] + bv, 0.f);
        float v2 = fmaxf(acc[m2][ni][2] + bv, 0.f);
        float v3 = fmaxf(acc[m2][ni][3] + bv, 0.f);
        uint2 w; w.x = pkbf(v0, v1); w.y = pkbf(v2, v3);
        *(uint2*)&epi[e*136 + m] = w;
      }
    }
    __syncthreads();
    const int e2 = t >> 1, mc = (t & 1) * 64;   // e2 0..127, mc 0/64
    const int h = h0 + (e2 >> 6), d = e2 & 63;
    const int sb = (s0m >> 6) + (mc >> 6);
    u16* dst = Vt64 + (((size_t)(b * NH + h) * 32 + sb) * 64 + d) * 64;
    #pragma unroll
    for (int i = 0; i < 8; ++i)
      *(uint4*)(dst + i*8) = *(const uint4*)&epi[e2*136 + mc + i*8];
  } else {
    // stage C[m][e] (stride 136); coalesced rows -> Qw/Kw[bh][s][dh]
    #pragma unroll
    for (int m2 = 0; m2 < 4; ++m2) {
      #pragma unroll
      for (int ni = 0; ni < 4; ++ni) {
        int e = wc*64 + ni*16 + fr;
        float bv = bias[n0 + e];
        #pragma unroll
        for (int r = 0; r < 4; ++r) {
          float v = acc[m2][ni][r] + bv;
          if (z == 0) v *= QSCALE;
          v = fmaxf(v, 0.f);
          epi[(wr*64 + m2*16 + fg*4 + r)*136 + e] = bfbits(v);
        }
      }
    }
    __syncthreads();
    const int mrow = t >> 1, hf = t & 1;
    u16* dst = ((z == 0) ? Qw : Kw) +
               (((size_t)(b * NH + h0 + hf)) * S_LEN + s0m + mrow) * DHD;
    #pragma unroll
    for (int i = 0; i < 8; ++i)
      *(uint4*)(dst + i*8) = *(const uint4*)&epi[mrow*136 + hf*64 + i*8];
  }
}

// longest-first block table (chunk = 6 steps): 51 units per bh.
// len-6 chunks first (desc qb), then len-4 finals, then len-2 finals.
static __device__ const uint8_t QBT[51] = {
  15,15,15,15,15, 14,14,14,14,14, 13,13,13,13, 12,12,12,12, 11,11,11,11,
  10,10,10, 9,9,9, 8,8,8, 7,7, 6,6, 5,5, 4, 3, 2,
  13,10,7,4,1, 15,12,9,6,3,0};
static __device__ const uint8_t CKT[51] = {
  0,1,2,3,4, 0,1,2,3,4, 0,1,2,3, 0,1,2,3, 0,1,2,3,
  0,1,2, 0,1,2, 0,1,2, 0,1, 0,1, 0,1, 0, 0, 0,
  4,3,2,1,0, 5,4,3,2,1,0};

// ---------------------------------------------------------------------------
// Flash attention (R13 mechanics, chunk=6): 4 waves/block, double-buffered
// 64-row K/V LDS tiles via global_load_lds; unnormalized p=exp2(s).
// 816 blocks -> ~3.2 blocks/CU co-resident chains.
// ---------------------------------------------------------------------------
__launch_bounds__(256, 3)
__global__ void attn_kernel(const u16* __restrict__ Qw, const u16* __restrict__ Kw,
                            const u16* __restrict__ Vt64, u16* __restrict__ Opart,
                            float* __restrict__ lbuf, float* __restrict__ out) {
  __shared__ u16 KLDS[2][4096];
  __shared__ u16 VLDS[2][4096];
  const int t = threadIdx.x;
  const int lane = t & 63;
  const int wid = t >> 6;
  const int lam = lane & 31;
  const int hi = lane >> 5;
  const int h8 = hi << 3, h4 = hi << 2;
  const int bid = blockIdx.x;
  const int bh = bid & 15;              // xcd = bid&7
  const int u = bid >> 4;               // 0..50
  const int qb = QBT[u], chunk = CKT[u];
  const int steps_total = (qb + 1) * 2;
  const int sc0 = chunk * 6;
  const int sc1e = sc0 + 6;
  const int sc1 = (sc1e < steps_total) ? sc1e : steps_total;
  const int t32 = qb * 4 + wid;
  const int q0 = qb * 128 + wid * 32;

  const u16* __restrict__ Qh = Qw + (size_t)bh * S_LEN * DHD;
  const u16* __restrict__ Kh = Kw + (size_t)bh * S_LEN * DHD;
  const u16* __restrict__ V64 = Vt64 + (size_t)bh * 32 * 64 * 64;

  bf16x8 qf[4];
  #pragma unroll
  for (int c = 0; c < 4; ++c)
    qf[c] = *(const bf16x8*)(Qh + (size_t)(q0 + lam) * DHD + c*16 + h8);

  const int lrow = lane >> 3;           // 0..7 within chunk
  const int lblk = lane & 7;
  auto stage = [&](int bf, int s) {
    #pragma unroll
    for (int i = 0; i < 2; ++i) {       // K,V: 8 chunks of 1KB each, 2 per wave
      int c = wid * 2 + i;
      int r = c * 8 + lrow;             // 0..63
      int sw = (lblk ^ (r & 7)) << 3;   // XOR-pre-swizzled source block (u16)
      gload16(Kh + (size_t)(s * 64 + r) * 64 + sw, &KLDS[bf][c * 512]);
      gload16(V64 + ((size_t)s * 64 + r) * 64 + sw, &VLDS[bf][c * 512]);
    }
  };

  f32x16 o0 = {}, o1 = {};
  float lsum = 0.f;

  auto softpack = [&](const f32x16& sc, bool msk, bf16x8& pb0v, bf16x8& pb1v) {
    float p[16];
    #pragma unroll
    for (int r = 0; r < 16; ++r) {
      float ev = __builtin_amdgcn_exp2f(sc[r]);
      int kc = (r & 3) + ((r >> 2) << 3) + h4;
      if (msk && kc > lam) ev = 0.f;
      p[r] = ev;
      lsum += ev;
    }
    uint32_t X0 = pkbf(p[0], p[1]),  X1 = pkbf(p[2], p[3]);
    uint32_t X2 = pkbf(p[4], p[5]),  X3 = pkbf(p[6], p[7]);
    uint32_t X4 = pkbf(p[8], p[9]),  X5 = pkbf(p[10], p[11]);
    uint32_t X6 = pkbf(p[12], p[13]), X7 = pkbf(p[14], p[15]);
    asm("v_permlane32_swap_b32 %0, %1" : "+v"(X0), "+v"(X2));
    asm("v_permlane32_swap_b32 %0, %1" : "+v"(X1), "+v"(X3));
    asm("v_permlane32_swap_b32 %0, %1" : "+v"(X4), "+v"(X6));
    asm("v_permlane32_swap_b32 %0, %1" : "+v"(X5), "+v"(X7));
    union U8 { uint32_t u[4]; bf16x8 v; };
    U8 a, bU;
    a.u[0] = X0; a.u[1] = X1; a.u[2] = X2; a.u[3] = X3;
    bU.u[0] = X4; bU.u[1] = X5; bU.u[2] = X6; bU.u[3] = X7;
    pb0v = a.v; pb1v = bU.v;
  };

  stage(0, sc0);
  int cb = 0;
  for (int s = sc0; s < sc1; ++s) {
    __syncthreads();                    // drains prior stage (compiler vmcnt)
    if (s + 1 < sc1) stage(cb ^ 1, s + 1);
    const int d2 = t32 - 2 * s;         // A computes if >=0 (diag ==0); B if >=1 (diag ==1)
    bf16x8 a0, a1, b0v, b1v;
    f32x16 sA = {}, sB = {};
    if (d2 >= 0) {
      bf16x8 kA[4];
      #pragma unroll
      for (int c = 0; c < 4; ++c) {
        int r = lam, e = ((2*c + hi) ^ (r & 7)) * 8;
        kA[c] = *(const bf16x8*)&KLDS[cb][r*64 + e];
      }
      __builtin_amdgcn_s_setprio(1);
      #pragma unroll
      for (int c = 0; c < 4; ++c)
        sA = __builtin_amdgcn_mfma_f32_32x32x16_bf16(kA[c], qf[c], sA, 0, 0, 0);
      __builtin_amdgcn_s_setprio(0);
    }
    if (d2 >= 1) {
      bf16x8 kB[4];
      #pragma unroll
      for (int c = 0; c < 4; ++c) {
        int r = 32 + lam, e = ((2*c + hi) ^ (r & 7)) * 8;
        kB[c] = *(const bf16x8*)&KLDS[cb][r*64 + e];
      }
      __builtin_amdgcn_s_setprio(1);
      #pragma unroll
      for (int c = 0; c < 4; ++c)
        sB = __builtin_amdgcn_mfma_f32_32x32x16_bf16(kB[c], qf[c], sB, 0, 0, 0);
      __builtin_amdgcn_s_setprio(0);
    }
    if (d2 >= 0) softpack(sA, d2 == 0, a0, a1);
    if (d2 >= 1) softpack(sB, d2 == 1, b0v, b1v);
    if (d2 >= 0) {
      bf16x8 v0[2], v1[2];
      #pragma unroll
      for (int c2 = 0; c2 < 2; ++c2) {
        int r0 = lam,      e0 = ((2*c2 + hi) ^ (r0 & 7)) * 8;
        int r1 = 32 + lam, e1 = ((2*c2 + hi) ^ (r1 & 7)) * 8;
        v0[c2] = *(const bf16x8*)&VLDS[cb][r0*64 + e0];
        v1[c2] = *(const bf16x8*)&VLDS[cb][r1*64 + e1];
      }
      __builtin_amdgcn_s_setprio(1);
      o0 = __builtin_amdgcn_mfma_f32_32x32x16_bf16(v0[0], a0, o0, 0, 0, 0);
      o0 = __builtin_amdgcn_mfma_f32_32x32x16_bf16(v0[1], a1, o0, 0, 0, 0);
      o1 = __builtin_amdgcn_mfma_f32_32x32x16_bf16(v1[0], a0, o1, 0, 0, 0);
      o1 = __builtin_amdgcn_mfma_f32_32x32x16_bf16(v1[1], a1, o1, 0, 0, 0);
      __builtin_amdgcn_s_setprio(0);
    }
    if (d2 >= 1) {
      bf16x8 v0[2], v1[2];
      #pragma unroll
      for (int c2 = 0; c2 < 2; ++c2) {
        int r0 = lam,      e0 = ((4 + 2*c2 + hi) ^ (r0 & 7)) * 8;
        int r1 = 32 + lam, e1 = ((4 + 2*c2 + hi) ^ (r1 & 7)) * 8;
        v0[c2] = *(const bf16x8*)&VLDS[cb][r0*64 + e0];
        v1[c2] = *(const bf16x8*)&VLDS[cb][r1*64 + e1];
      }
      __builtin_amdgcn_s_setprio(1);
      o0 = __builtin_amdgcn_mfma_f32_32x32x16_bf16(v0[0], b0v, o0, 0, 0, 0);
      o0 = __builtin_amdgcn_mfma_f32_32x32x16_bf16(v0[1], b1v, o0, 0, 0, 0);
      o1 = __builtin_amdgcn_mfma_f32_32x32x16_bf16(v1[0], b0v, o1, 0, 0, 0);
      o1 = __builtin_amdgcn_mfma_f32_32x32x16_bf16(v1[1], b1v, o1, 0, 0, 0);
      __builtin_amdgcn_s_setprio(0);
    }
    cb ^= 1;
  }

  float l = lsum + __shfl_xor(lsum, 32);

  if (qb <= 2) {
    // single-chunk tile: direct normalized write
    const int b = bh >> 3, hh = bh & 7;
    const float inv = 1.0f / l;
    float* orow = out + (((size_t)(hh * NB + b)) * S_LEN + (q0 + lam)) * DHD;
    #pragma unroll
    for (int r = 0; r < 16; ++r) {
      int d = (r & 3) + ((r >> 2) << 3) + h4;
      orow[d] = o0[r] * inv;
      orow[d + 32] = o1[r] * inv;
    }
  } else {
    const int slot = slot_of(bh, t32, chunk);
    uint32_t w[16] __attribute__((aligned(16)));
    #pragma unroll
    for (int m = 0; m < 8; ++m) {
      w[m]     = pkbf(o0[2*m], o0[2*m+1]);
      w[8 + m] = pkbf(o1[2*m], o1[2*m+1]);
    }
    u16* op = Opart + (size_t)slot * 2048 + (size_t)lane * 32;
    #pragma unroll
    for (int i = 0; i < 4; ++i)
      *(uint4*)(op + i*8) = *(const uint4*)&w[i*4];
    if (lane < 32) lbuf[slot * 32 + lane] = l;
  }
}

// ---------------------------------------------------------------------------
// Combine split-K partials for tiles with qb>=3 (t32 12..63): plain sums.
// ---------------------------------------------------------------------------
__launch_bounds__(256)
__global__ void reduce_kernel(const u16* __restrict__ Opart,
                              const float* __restrict__ lbuf,
                              float* __restrict__ out) {
  const int t = threadIdx.x;
  const int unit = blockIdx.x * 4 + (t >> 6);   // 0..831
  const int bh = unit & 15;
  const int ti = 12 + (unit >> 4);              // t32 12..63
  const int qb = ti >> 2;
  const int nc = (qb + 3) / 3;                  // 2..6
  const int lane = t & 63;
  const int lam = lane & 31;
  const int h4 = (lane >> 5) << 2;
  const int slot0 = slot_of(bh, ti, 0);

  float O[32];
  #pragma unroll
  for (int i = 0; i < 32; ++i) O[i] = 0.f;
  float L = 0.f;

  for (int c = 0; c < nc; ++c) {
    const u16* op = Opart + (size_t)(slot0 + c) * 2048 + (size_t)lane * 32;
    L += lbuf[(slot0 + c) * 32 + lam];
    #pragma unroll
    for (int i = 0; i < 4; ++i) {
      uint4 v = *(const uint4*)(op + i*8);
      uint32_t a[4] = {v.x, v.y, v.z, v.w};
      #pragma unroll
      for (int jj = 0; jj < 4; ++jj) {
        O[i*8 + 2*jj]     += bits2f((u16)(a[jj] & 0xFFFFu));
        O[i*8 + 2*jj + 1] += bits2f((u16)(a[jj] >> 16));
      }
    }
  }

  const int b = bh >> 3, hh = bh & 7;
  const float inv = 1.0f / L;
  float* orow = out + (((size_t)(hh * NB + b)) * S_LEN + (ti*32 + lam)) * DHD;
  #pragma unroll
  for (int r = 0; r < 16; ++r) {
    int d = (r & 3) + ((r >> 2) << 3) + h4;
    orow[d] = O[r] * inv;
    orow[d + 32] = O[16 + r] * inv;
  }
}

extern "C" void kernel_launch(void* const* d_in, const int* in_sizes, int n_in,
                              void* d_out, int out_size, void* d_ws, size_t ws_size,
                              hipStream_t stream) {
  const float* q = (const float*)d_in[0];
  const float* k = (const float*)d_in[1];
  const float* v = (const float*)d_in[2];
  const float* W = (const float*)d_in[3];
  const float* b = (const float*)d_in[4];

  const size_t elems = (size_t)NB * NH * S_LEN * DHD;  // 2,097,152
  u16* Qw = (u16*)d_ws;
  u16* Kw = Qw + elems;
  u16* Vt64 = Kw + elems;
  u16* Opart = Vt64 + elems;                           // 3072 slots * 4 KiB = 12 MiB
  float* lbuf = (float*)(Opart + (size_t)16 * SLOTS_PER_BH * 2048); // 384 KiB

  proj_kernel<<<dim3(384), dim3(256), 0, stream>>>(q, k, v, W, b, Qw, Kw, Vt64);

  attn_kernel<<<dim3(816), dim3(256), 0, stream>>>(Qw, Kw, Vt64, Opart, lbuf, (float*)d_out);

  reduce_kernel<<<dim3(208), dim3(256), 0, stream>>>(Opart, lbuf, (float*)d_out);
}

// Round 21
// 50.490 us; speedup vs baseline: 1.4490x; 1.0039x over previous
//
#include <hip/hip_runtime.h>
#include <hip/hip_bf16.h>
#include <cstdint>
#include <cstddef>

typedef __bf16 bf16_t;
typedef bf16_t bf16x8 __attribute__((ext_vector_type(8)));
typedef float f32x4 __attribute__((ext_vector_type(4)));
typedef float f32x16 __attribute__((ext_vector_type(16)));
typedef unsigned short u16;
typedef u16 u16x8 __attribute__((ext_vector_type(8)));

#define S_LEN 2048
#define NB 2
#define NH 8
#define DHD 64
#define DM 512

static __device__ __forceinline__ u16 bfbits(float f) {
  union { __bf16 h; u16 u; } c; c.h = (__bf16)f; return c.u;
}
static __device__ __forceinline__ float bits2f(u16 b) {
  union { u16 u; __bf16 h; } c; c.u = b; return (float)c.h;
}
static __device__ __forceinline__ uint32_t pkbf(float a, float b) {
  union { __bf16 h[2]; uint32_t u; } c;
  c.h[0] = (__bf16)a; c.h[1] = (__bf16)b;
  return c.u;
}
// async global->LDS, 16B per lane; LDS dest is wave-uniform base + lane*16
static __device__ __forceinline__ void gload16(const void* g, void* l) {
  __builtin_amdgcn_global_load_lds(
      (const __attribute__((address_space(1))) uint32_t*)g,
      (__attribute__((address_space(3))) uint32_t*)l, 16, 0, 0);
}

// slots for split-K partials: per bh, qb 5..15, 4 waves, nc chunks
static __device__ __forceinline__ int slot_of(int bh, int t32, int chunk) {
  int qb = t32 >> 2;
  int nc = (2 * (qb + 1) + 9) / 10;
  int off;
  if (qb < 10) off = (qb - 5) * 8;
  else if (qb < 15) off = 40 + (qb - 10) * 12;
  else off = 100;
  return bh * 116 + off + (t32 & 3) * nc + chunk;
}

// ---------------------------------------------------------------------------
// Projection GEMM: P = relu(X @ W^T + b); Q pre-scaled by 0.125*log2(e).
// 128x128 tile (16 MFMA/wave/step covers the fixed stage latency inside one
// chain). BK=32, 16 steps, 2 LDS bufs; fp32 staged via global_load_lds
// (XOR-pre-swizzled source, linear LDS, XOR read); fp32->bf16 cvt at
// fragment build. Grid 384 = 8 xcd * 12 m * 4 n.
// ---------------------------------------------------------------------------
__launch_bounds__(256, 2)
__global__ void proj_kernel(const float* __restrict__ Xq, const float* __restrict__ Xk,
                            const float* __restrict__ Xv, const float* __restrict__ W,
                            const float* __restrict__ bias,
                            u16* __restrict__ Qw, u16* __restrict__ Kw,
                            u16* __restrict__ Vt64) {
  __shared__ __align__(16) float BUF[2][8192];   // per buf: A 128x32 @0, B 128x32 @4096
  const int bid = blockIdx.x;
  const int xcd = bid & 7;
  const int u = bid >> 3;               // 0..47
  const int n0 = (u & 3) * 128;
  const int mIdx = u >> 2;              // 0..11
  const int mg = (xcd * 12 + mIdx) * 128;
  const int z = mg >> 12;               // 0..2
  const int m_in = mg & 4095;
  const int b = m_in >> 11;
  const int s0m = m_in & (S_LEN - 1);
  const int h0 = n0 >> 6;               // first of 2 heads in this n-span
  const float* __restrict__ X = (z == 0) ? Xq : ((z == 1) ? Xk : Xv);
  X += (size_t)m_in * DM;

  const int t = threadIdx.x;
  const int lane = t & 63;
  const int wid = t >> 6;
  const int wr = wid >> 1, wc = wid & 1;
  const int fr = lane & 15, fg = lane >> 4;

  f32x4 acc[4][4] = {};

  const int lrow = lane >> 3;           // 0..7 within chunk
  const int lblk = lane & 7;            // 16B block within 128B row

  auto stage = [&](int bf, int k0) {
    #pragma unroll
    for (int i = 0; i < 4; ++i) {       // A: 16 chunks of 1KB (8 rows), 4/wave
      int c = wid * 4 + i;
      int r = c * 8 + lrow;
      gload16(X + (size_t)r * DM + k0 + ((lblk ^ (r & 7)) << 2), &BUF[bf][c * 256]);
    }
    #pragma unroll
    for (int i = 0; i < 4; ++i) {       // B: 16 chunks, 4/wave
      int c = wid * 4 + i;
      int r = c * 8 + lrow;
      gload16(W + (size_t)(n0 + r) * DM + k0 + ((lblk ^ (r & 7)) << 2),
              &BUF[bf][4096 + c * 256]);
    }
  };

  stage(0, 0);
  int cb = 0;
  for (int i = 0; i < 16; ++i) {
    __syncthreads();                    // drains prior stage (compiler vmcnt)
    if (i < 15) stage(cb ^ 1, (i + 1) * 32);
    const float* Ac = BUF[cb];
    bf16x8 af[4], bfr[4];
    #pragma unroll
    for (int m2 = 0; m2 < 4; ++m2) {
      int r = wr*64 + m2*16 + fr;
      f32x4 lo = *(const f32x4*)&Ac[r*32 + (((2*fg)     ^ (r & 7)) << 2)];
      f32x4 hi = *(const f32x4*)&Ac[r*32 + (((2*fg + 1) ^ (r & 7)) << 2)];
      union { u16x8 s; bf16x8 v; } f;
      f.s[0]=bfbits(lo[0]); f.s[1]=bfbits(lo[1]); f.s[2]=bfbits(lo[2]); f.s[3]=bfbits(lo[3]);
      f.s[4]=bfbits(hi[0]); f.s[5]=bfbits(hi[1]); f.s[6]=bfbits(hi[2]); f.s[7]=bfbits(hi[3]);
      af[m2] = f.v;
    }
    #pragma unroll
    for (int ni = 0; ni < 4; ++ni) {
      int r = wc*64 + ni*16 + fr;
      f32x4 lo = *(const f32x4*)&Ac[4096 + r*32 + (((2*fg)     ^ (r & 7)) << 2)];
      f32x4 hi = *(const f32x4*)&Ac[4096 + r*32 + (((2*fg + 1) ^ (r & 7)) << 2)];
      union { u16x8 s; bf16x8 v; } f;
      f.s[0]=bfbits(lo[0]); f.s[1]=bfbits(lo[1]); f.s[2]=bfbits(lo[2]); f.s[3]=bfbits(lo[3]);
      f.s[4]=bfbits(hi[0]); f.s[5]=bfbits(hi[1]); f.s[6]=bfbits(hi[2]); f.s[7]=bfbits(hi[3]);
      bfr[ni] = f.v;
    }
    __builtin_amdgcn_s_setprio(1);
    #pragma unroll
    for (int m2 = 0; m2 < 4; ++m2)
      #pragma unroll
      for (int ni = 0; ni < 4; ++ni)
        acc[m2][ni] = __builtin_amdgcn_mfma_f32_16x16x32_bf16(af[m2], bfr[ni], acc[m2][ni], 0, 0, 0);
    __builtin_amdgcn_s_setprio(0);
    cb ^= 1;
  }
  __syncthreads();

  const float QSCALE = 0.125f * 1.44269504089f;
  u16* epi = (u16*)&BUF[0][0];          // 128 x 136 u16 = 34 KB, fits 64 KB pool

  if (z == 2) {
    // stage C^T[e][m] (stride 136); coalesced rows -> Vt64[bh][s/64][d][s%64]
    #pragma unroll
    for (int m2 = 0; m2 < 4; ++m2) {
      #pragma unroll
      for (int ni = 0; ni < 4; ++ni) {
        int e = wc*64 + ni*16 + fr;
        int m = wr*64 + m2*16 + fg*4;
        float bv = bias[n0 + e];
        float v0 = fmaxf(acc[m2][ni][0] + bv, 0.f);
        float v1 = fmaxf(acc[m2][ni][1] + bv, 0.f);
        float v2 = fmaxf(acc[m2][ni][2] + bv, 0.f);
        float v3 = fmaxf(acc[m2][ni][3] + bv, 0.f);
        uint2 w; w.x = pkbf(v0, v1); w.y = pkbf(v2, v3);
        *(uint2*)&epi[e*136 + m] = w;
      }
    }
    __syncthreads();
    const int e2 = t >> 1, mc = (t & 1) * 64;   // e2 0..127, mc 0/64
    const int h = h0 + (e2 >> 6), d = e2 & 63;
    const int sb = (s0m >> 6) + (mc >> 6);
    u16* dst = Vt64 + (((size_t)(b * NH + h) * 32 + sb) * 64 + d) * 64;
    #pragma unroll
    for (int i = 0; i < 8; ++i)
      *(uint4*)(dst + i*8) = *(const uint4*)&epi[e2*136 + mc + i*8];
  } else {
    // stage C[m][e] (stride 136); coalesced rows -> Qw/Kw[bh][s][dh]
    #pragma unroll
    for (int m2 = 0; m2 < 4; ++m2) {
      #pragma unroll
      for (int ni = 0; ni < 4; ++ni) {
        int e = wc*64 + ni*16 + fr;
        float bv = bias[n0 + e];
        #pragma unroll
        for (int r = 0; r < 4; ++r) {
          float v = acc[m2][ni][r] + bv;
          if (z == 0) v *= QSCALE;
          v = fmaxf(v, 0.f);
          epi[(wr*64 + m2*16 + fg*4 + r)*136 + e] = bfbits(v);
        }
      }
    }
    __syncthreads();
    const int mrow = t >> 1, hf = t & 1;
    u16* dst = ((z == 0) ? Qw : Kw) +
               (((size_t)(b * NH + h0 + hf)) * S_LEN + s0m + mrow) * DHD;
    #pragma unroll
    for (int i = 0; i < 8; ++i)
      *(uint4*)(dst + i*8) = *(const uint4*)&epi[mrow*136 + hf*64 + i*8];
  }
}

// longest-first block table: (qb, chunk) for the 34 blocks per bh
static __device__ const uint8_t QBT[34] = {4,5,6,7,8,9,9,10,10,11,11,12,12,13,13,14,14,14,15,15,15,
                                           3,8,13, 2,7,12, 1,6,11, 0,5,10,15};
static __device__ const uint8_t CKT[34] = {0,0,0,0,0,0,1,0,1,0,1,0,1,0,1,0,1,2,0,1,2,
                                           0,1,2, 0,1,2, 0,1,2, 0,1,2,3};

// ---------------------------------------------------------------------------
// Flash attention: 4 waves/block, double-buffered 64-row K/V LDS tiles via
// global_load_lds (XOR-pre-swizzled source); unnormalized p=exp2(s)
// (post-ReLU scores >= 0; log2e folded into Q); split-K chunks <=10 steps.
// ---------------------------------------------------------------------------
__launch_bounds__(256, 3)
__global__ void attn_kernel(const u16* __restrict__ Qw, const u16* __restrict__ Kw,
                            const u16* __restrict__ Vt64, u16* __restrict__ Opart,
                            float* __restrict__ lbuf, float* __restrict__ out) {
  __shared__ u16 KLDS[2][4096];
  __shared__ u16 VLDS[2][4096];
  const int t = threadIdx.x;
  const int lane = t & 63;
  const int wid = t >> 6;
  const int lam = lane & 31;
  const int hi = lane >> 5;
  const int h8 = hi << 3, h4 = hi << 2;
  const int bid = blockIdx.x;
  const int bh = bid & 15;              // xcd = bid&7
  const int u = bid >> 4;               // 0..33
  const int qb = QBT[u], chunk = CKT[u];
  const int steps_total = (qb + 1) * 2;
  const int sc0 = chunk * 10;
  const int sc1e = sc0 + 10;
  const int sc1 = (sc1e < steps_total) ? sc1e : steps_total;
  const int t32 = qb * 4 + wid;
  const int q0 = qb * 128 + wid * 32;

  const u16* __restrict__ Qh = Qw + (size_t)bh * S_LEN * DHD;
  const u16* __restrict__ Kh = Kw + (size_t)bh * S_LEN * DHD;
  const u16* __restrict__ V64 = Vt64 + (size_t)bh * 32 * 64 * 64;

  bf16x8 qf[4];
  #pragma unroll
  for (int c = 0; c < 4; ++c)
    qf[c] = *(const bf16x8*)(Qh + (size_t)(q0 + lam) * DHD + c*16 + h8);

  const int lrow = lane >> 3;           // 0..7 within chunk
  const int lblk = lane & 7;
  auto stage = [&](int bf, int s) {
    #pragma unroll
    for (int i = 0; i < 2; ++i) {       // K,V: 8 chunks of 1KB each, 2 per wave
      int c = wid * 2 + i;
      int r = c * 8 + lrow;             // 0..63
      int sw = (lblk ^ (r & 7)) << 3;   // XOR-pre-swizzled source block (u16)
      gload16(Kh + (size_t)(s * 64 + r) * 64 + sw, &KLDS[bf][c * 512]);
      gload16(V64 + ((size_t)s * 64 + r) * 64 + sw, &VLDS[bf][c * 512]);
    }
  };

  f32x16 o0 = {}, o1 = {};
  float lsum = 0.f;

  auto softpack = [&](const f32x16& sc, bool msk, bf16x8& pb0v, bf16x8& pb1v) {
    float p[16];
    #pragma unroll
    for (int r = 0; r < 16; ++r) {
      float ev = __builtin_amdgcn_exp2f(sc[r]);
      int kc = (r & 3) + ((r >> 2) << 3) + h4;
      if (msk && kc > lam) ev = 0.f;
      p[r] = ev;
      lsum += ev;
    }
    uint32_t X0 = pkbf(p[0], p[1]),  X1 = pkbf(p[2], p[3]);
    uint32_t X2 = pkbf(p[4], p[5]),  X3 = pkbf(p[6], p[7]);
    uint32_t X4 = pkbf(p[8], p[9]),  X5 = pkbf(p[10], p[11]);
    uint32_t X6 = pkbf(p[12], p[13]), X7 = pkbf(p[14], p[15]);
    asm("v_permlane32_swap_b32 %0, %1" : "+v"(X0), "+v"(X2));
    asm("v_permlane32_swap_b32 %0, %1" : "+v"(X1), "+v"(X3));
    asm("v_permlane32_swap_b32 %0, %1" : "+v"(X4), "+v"(X6));
    asm("v_permlane32_swap_b32 %0, %1" : "+v"(X5), "+v"(X7));
    union U8 { uint32_t u[4]; bf16x8 v; };
    U8 a, bU;
    a.u[0] = X0; a.u[1] = X1; a.u[2] = X2; a.u[3] = X3;
    bU.u[0] = X4; bU.u[1] = X5; bU.u[2] = X6; bU.u[3] = X7;
    pb0v = a.v; pb1v = bU.v;
  };

  stage(0, sc0);
  int cb = 0;
  for (int s = sc0; s < sc1; ++s) {
    __syncthreads();                    // drains prior stage (compiler vmcnt)
    if (s + 1 < sc1) stage(cb ^ 1, s + 1);
    const int d2 = t32 - 2 * s;         // A computes if >=0 (diag ==0); B if >=1 (diag ==1)
    bf16x8 a0, a1, b0v, b1v;
    f32x16 sA = {}, sB = {};
    if (d2 >= 0) {
      bf16x8 kA[4];
      #pragma unroll
      for (int c = 0; c < 4; ++c) {
        int r = lam, e = ((2*c + hi) ^ (r & 7)) * 8;
        kA[c] = *(const bf16x8*)&KLDS[cb][r*64 + e];
      }
      __builtin_amdgcn_s_setprio(1);
      #pragma unroll
      for (int c = 0; c < 4; ++c)
        sA = __builtin_amdgcn_mfma_f32_32x32x16_bf16(kA[c], qf[c], sA, 0, 0, 0);
      __builtin_amdgcn_s_setprio(0);
    }
    if (d2 >= 1) {
      bf16x8 kB[4];
      #pragma unroll
      for (int c = 0; c < 4; ++c) {
        int r = 32 + lam, e = ((2*c + hi) ^ (r & 7)) * 8;
        kB[c] = *(const bf16x8*)&KLDS[cb][r*64 + e];
      }
      __builtin_amdgcn_s_setprio(1);
      #pragma unroll
      for (int c = 0; c < 4; ++c)
        sB = __builtin_amdgcn_mfma_f32_32x32x16_bf16(kB[c], qf[c], sB, 0, 0, 0);
      __builtin_amdgcn_s_setprio(0);
    }
    if (d2 >= 0) softpack(sA, d2 == 0, a0, a1);
    if (d2 >= 1) softpack(sB, d2 == 1, b0v, b1v);
    if (d2 >= 0) {
      bf16x8 v0[2], v1[2];
      #pragma unroll
      for (int c2 = 0; c2 < 2; ++c2) {
        int r0 = lam,      e0 = ((2*c2 + hi) ^ (r0 & 7)) * 8;
        int r1 = 32 + lam, e1 = ((2*c2 + hi) ^ (r1 & 7)) * 8;
        v0[c2] = *(const bf16x8*)&VLDS[cb][r0*64 + e0];
        v1[c2] = *(const bf16x8*)&VLDS[cb][r1*64 + e1];
      }
      __builtin_amdgcn_s_setprio(1);
      o0 = __builtin_amdgcn_mfma_f32_32x32x16_bf16(v0[0], a0, o0, 0, 0, 0);
      o0 = __builtin_amdgcn_mfma_f32_32x32x16_bf16(v0[1], a1, o0, 0, 0, 0);
      o1 = __builtin_amdgcn_mfma_f32_32x32x16_bf16(v1[0], a0, o1, 0, 0, 0);
      o1 = __builtin_amdgcn_mfma_f32_32x32x16_bf16(v1[1], a1, o1, 0, 0, 0);
      __builtin_amdgcn_s_setprio(0);
    }
    if (d2 >= 1) {
      bf16x8 v0[2], v1[2];
      #pragma unroll
      for (int c2 = 0; c2 < 2; ++c2) {
        int r0 = lam,      e0 = ((4 + 2*c2 + hi) ^ (r0 & 7)) * 8;
        int r1 = 32 + lam, e1 = ((4 + 2*c2 + hi) ^ (r1 & 7)) * 8;
        v0[c2] = *(const bf16x8*)&VLDS[cb][r0*64 + e0];
        v1[c2] = *(const bf16x8*)&VLDS[cb][r1*64 + e1];
      }
      __builtin_amdgcn_s_setprio(1);
      o0 = __builtin_amdgcn_mfma_f32_32x32x16_bf16(v0[0], b0v, o0, 0, 0, 0);
      o0 = __builtin_amdgcn_mfma_f32_32x32x16_bf16(v0[1], b1v, o0, 0, 0, 0);
      o1 = __builtin_amdgcn_mfma_f32_32x32x16_bf16(v1[0], b0v, o1, 0, 0, 0);
      o1 = __builtin_amdgcn_mfma_f32_32x32x16_bf16(v1[1], b1v, o1, 0, 0, 0);
      __builtin_amdgcn_s_setprio(0);
    }
    cb ^= 1;
  }

  float l = lsum + __shfl_xor(lsum, 32);

  if (qb <= 4) {
    const int b = bh >> 3, hh = bh & 7;
    const float inv = 1.0f / l;
    float* orow = out + (((size_t)(hh * NB + b)) * S_LEN + (q0 + lam)) * DHD;
    #pragma unroll
    for (int r = 0; r < 16; ++r) {
      int d = (r & 3) + ((r >> 2) << 3) + h4;
      orow[d] = o0[r] * inv;
      orow[d + 32] = o1[r] * inv;
    }
  } else {
    const int slot = slot_of(bh, t32, chunk);
    uint32_t w[16] __attribute__((aligned(16)));
    #pragma unroll
    for (int m = 0; m < 8; ++m) {
      w[m]     = pkbf(o0[2*m], o0[2*m+1]);
      w[8 + m] = pkbf(o1[2*m], o1[2*m+1]);
    }
    u16* op = Opart + (size_t)slot * 2048 + (size_t)lane * 32;
    #pragma unroll
    for (int i = 0; i < 4; ++i)
      *(uint4*)(op + i*8) = *(const uint4*)&w[i*4];
    if (lane < 32) lbuf[slot * 32 + lane] = l;
  }
}

// ---------------------------------------------------------------------------
// Combine split-K partials for tiles with qb>=5 (t32 20..63): plain sums.
// ---------------------------------------------------------------------------
__launch_bounds__(256)
__global__ void reduce_kernel(const u16* __restrict__ Opart,
                              const float* __restrict__ lbuf,
                              float* __restrict__ out) {
  const int t = threadIdx.x;
  const int unit = blockIdx.x * 4 + (t >> 6);   // 0..703
  const int bh = unit & 15;
  const int ti = 20 + (unit >> 4);              // t32 20..63
  const int qb = ti >> 2;
  const int nc = (2 * (qb + 1) + 9) / 10;       // 2..4
  const int lane = t & 63;
  const int lam = lane & 31;
  const int h4 = (lane >> 5) << 2;
  const int slot0 = slot_of(bh, ti, 0);

  float O[32];
  #pragma unroll
  for (int i = 0; i < 32; ++i) O[i] = 0.f;
  float L = 0.f;

  for (int c = 0; c < nc; ++c) {
    const u16* op = Opart + (size_t)(slot0 + c) * 2048 + (size_t)lane * 32;
    L += lbuf[(slot0 + c) * 32 + lam];
    #pragma unroll
    for (int i = 0; i < 4; ++i) {
      uint4 v = *(const uint4*)(op + i*8);
      uint32_t a[4] = {v.x, v.y, v.z, v.w};
      #pragma unroll
      for (int jj = 0; jj < 4; ++jj) {
        O[i*8 + 2*jj]     += bits2f((u16)(a[jj] & 0xFFFFu));
        O[i*8 + 2*jj + 1] += bits2f((u16)(a[jj] >> 16));
      }
    }
  }

  const int b = bh >> 3, hh = bh & 7;
  const float inv = 1.0f / L;
  float* orow = out + (((size_t)(hh * NB + b)) * S_LEN + (ti*32 + lam)) * DHD;
  #pragma unroll
  for (int r = 0; r < 16; ++r) {
    int d = (r & 3) + ((r >> 2) << 3) + h4;
    orow[d] = O[r] * inv;
    orow[d + 32] = O[16 + r] * inv;
  }
}

extern "C" void kernel_launch(void* const* d_in, const int* in_sizes, int n_in,
                              void* d_out, int out_size, void* d_ws, size_t ws_size,
                              hipStream_t stream) {
  const float* q = (const float*)d_in[0];
  const float* k = (const float*)d_in[1];
  const float* v = (const float*)d_in[2];
  const float* W = (const float*)d_in[3];
  const float* b = (const float*)d_in[4];

  const size_t elems = (size_t)NB * NH * S_LEN * DHD;  // 2,097,152
  u16* Qw = (u16*)d_ws;
  u16* Kw = Qw + elems;
  u16* Vt64 = Kw + elems;
  u16* Opart = Vt64 + elems;                           // 1856 slots * 4 KiB = 7.25 MiB
  float* lbuf = (float*)(Opart + (size_t)1856 * 2048); // 232 KiB

  proj_kernel<<<dim3(384), dim3(256), 0, stream>>>(q, k, v, W, b, Qw, Kw, Vt64);

  attn_kernel<<<dim3(544), dim3(256), 0, stream>>>(Qw, Kw, Vt64, Opart, lbuf, (float*)d_out);

  reduce_kernel<<<dim3(176), dim3(256), 0, stream>>>(Opart, lbuf, (float*)d_out);
}

// Round 22
// 49.354 us; speedup vs baseline: 1.4823x; 1.0230x over previous
//
#include <hip/hip_runtime.h>
#include <hip/hip_bf16.h>
#include <cstdint>
#include <cstddef>

typedef __bf16 bf16_t;
typedef bf16_t bf16x8 __attribute__((ext_vector_type(8)));
typedef float f32x4 __attribute__((ext_vector_type(4)));
typedef float f32x16 __attribute__((ext_vector_type(16)));
typedef unsigned short u16;
typedef u16 u16x8 __attribute__((ext_vector_type(8)));

#define S_LEN 2048
#define NB 2
#define NH 8
#define DHD 64
#define DM 512

static __device__ __forceinline__ u16 bfbits(float f) {
  union { __bf16 h; u16 u; } c; c.h = (__bf16)f; return c.u;
}
static __device__ __forceinline__ float bits2f(u16 b) {
  union { u16 u; __bf16 h; } c; c.u = b; return (float)c.h;
}
static __device__ __forceinline__ uint32_t pkbf(float a, float b) {
  union { __bf16 h[2]; uint32_t u; } c;
  c.h[0] = (__bf16)a; c.h[1] = (__bf16)b;
  return c.u;
}
// async global->LDS, 16B per lane; LDS dest is wave-uniform base + lane*16
static __device__ __forceinline__ void gload16(const void* g, void* l) {
  __builtin_amdgcn_global_load_lds(
      (const __attribute__((address_space(1))) uint32_t*)g,
      (__attribute__((address_space(3))) uint32_t*)l, 16, 0, 0);
}

// slots for split-K partials: per bh, qb 5..15, 4 waves, nc chunks
static __device__ __forceinline__ int slot_of(int bh, int t32, int chunk) {
  int qb = t32 >> 2;
  int nc = (2 * (qb + 1) + 9) / 10;
  int off;
  if (qb < 10) off = (qb - 5) * 8;
  else if (qb < 15) off = 40 + (qb - 10) * 12;
  else off = 100;
  return bh * 116 + off + (t32 & 3) * nc + chunk;
}

// ---------------------------------------------------------------------------
// Projection GEMM (R13 verbatim): P = relu(X @ W^T + b); Q scaled 0.125*log2e.
// 128x128 tile, BK=32, 16 steps, 2 LDS bufs; fp32 staged via global_load_lds
// (XOR-pre-swizzled source, linear LDS, XOR read); cvt at fragment build.
// ---------------------------------------------------------------------------
__launch_bounds__(256, 2)
__global__ void proj_kernel(const float* __restrict__ Xq, const float* __restrict__ Xk,
                            const float* __restrict__ Xv, const float* __restrict__ W,
                            const float* __restrict__ bias,
                            u16* __restrict__ Qw, u16* __restrict__ Kw,
                            u16* __restrict__ Vt64) {
  __shared__ __align__(16) float BUF[2][8192];   // per buf: A 128x32 @0, B 128x32 @4096
  const int bid = blockIdx.x;
  const int xcd = bid & 7;
  const int u = bid >> 3;               // 0..47
  const int n0 = (u & 3) * 128;
  const int mIdx = u >> 2;              // 0..11
  const int mg = (xcd * 12 + mIdx) * 128;
  const int z = mg >> 12;               // 0..2
  const int m_in = mg & 4095;
  const int b = m_in >> 11;
  const int s0m = m_in & (S_LEN - 1);
  const int h0 = n0 >> 6;               // first of 2 heads in this n-span
  const float* __restrict__ X = (z == 0) ? Xq : ((z == 1) ? Xk : Xv);
  X += (size_t)m_in * DM;

  const int t = threadIdx.x;
  const int lane = t & 63;
  const int wid = t >> 6;
  const int wr = wid >> 1, wc = wid & 1;
  const int fr = lane & 15, fg = lane >> 4;

  f32x4 acc[4][4] = {};

  const int lrow = lane >> 3;           // 0..7 within chunk
  const int lblk = lane & 7;            // 16B block within 128B row

  auto stage = [&](int bf, int k0) {
    #pragma unroll
    for (int i = 0; i < 4; ++i) {       // A: 16 chunks of 1KB (8 rows), 4/wave
      int c = wid * 4 + i;
      int r = c * 8 + lrow;
      gload16(X + (size_t)r * DM + k0 + ((lblk ^ (r & 7)) << 2), &BUF[bf][c * 256]);
    }
    #pragma unroll
    for (int i = 0; i < 4; ++i) {       // B: 16 chunks, 4/wave
      int c = wid * 4 + i;
      int r = c * 8 + lrow;
      gload16(W + (size_t)(n0 + r) * DM + k0 + ((lblk ^ (r & 7)) << 2),
              &BUF[bf][4096 + c * 256]);
    }
  };

  stage(0, 0);
  int cb = 0;
  for (int i = 0; i < 16; ++i) {
    __syncthreads();                    // drains prior stage (compiler vmcnt)
    if (i < 15) stage(cb ^ 1, (i + 1) * 32);
    const float* Ac = BUF[cb];
    bf16x8 af[4], bfr[4];
    #pragma unroll
    for (int m2 = 0; m2 < 4; ++m2) {
      int r = wr*64 + m2*16 + fr;
      f32x4 lo = *(const f32x4*)&Ac[r*32 + (((2*fg)     ^ (r & 7)) << 2)];
      f32x4 hi = *(const f32x4*)&Ac[r*32 + (((2*fg + 1) ^ (r & 7)) << 2)];
      union { u16x8 s; bf16x8 v; } f;
      f.s[0]=bfbits(lo[0]); f.s[1]=bfbits(lo[1]); f.s[2]=bfbits(lo[2]); f.s[3]=bfbits(lo[3]);
      f.s[4]=bfbits(hi[0]); f.s[5]=bfbits(hi[1]); f.s[6]=bfbits(hi[2]); f.s[7]=bfbits(hi[3]);
      af[m2] = f.v;
    }
    #pragma unroll
    for (int ni = 0; ni < 4; ++ni) {
      int r = wc*64 + ni*16 + fr;
      f32x4 lo = *(const f32x4*)&Ac[4096 + r*32 + (((2*fg)     ^ (r & 7)) << 2)];
      f32x4 hi = *(const f32x4*)&Ac[4096 + r*32 + (((2*fg + 1) ^ (r & 7)) << 2)];
      union { u16x8 s; bf16x8 v; } f;
      f.s[0]=bfbits(lo[0]); f.s[1]=bfbits(lo[1]); f.s[2]=bfbits(lo[2]); f.s[3]=bfbits(lo[3]);
      f.s[4]=bfbits(hi[0]); f.s[5]=bfbits(hi[1]); f.s[6]=bfbits(hi[2]); f.s[7]=bfbits(hi[3]);
      bfr[ni] = f.v;
    }
    __builtin_amdgcn_s_setprio(1);
    #pragma unroll
    for (int m2 = 0; m2 < 4; ++m2)
      #pragma unroll
      for (int ni = 0; ni < 4; ++ni)
        acc[m2][ni] = __builtin_amdgcn_mfma_f32_16x16x32_bf16(af[m2], bfr[ni], acc[m2][ni], 0, 0, 0);
    __builtin_amdgcn_s_setprio(0);
    cb ^= 1;
  }
  __syncthreads();

  const float QSCALE = 0.125f * 1.44269504089f;
  u16* epi = (u16*)&BUF[0][0];          // 128 x 136 u16 = 34 KB, fits 64 KB pool

  if (z == 2) {
    // stage C^T[e][m] (stride 136); coalesced rows -> Vt64[bh][s/64][d][s%64]
    #pragma unroll
    for (int m2 = 0; m2 < 4; ++m2) {
      #pragma unroll
      for (int ni = 0; ni < 4; ++ni) {
        int e = wc*64 + ni*16 + fr;
        int m = wr*64 + m2*16 + fg*4;
        float bv = bias[n0 + e];
        float v0 = fmaxf(acc[m2][ni][0] + bv, 0.f);
        float v1 = fmaxf(acc[m2][ni][1] + bv, 0.f);
        float v2 = fmaxf(acc[m2][ni][2] + bv, 0.f);
        float v3 = fmaxf(acc[m2][ni][3] + bv, 0.f);
        uint2 w; w.x = pkbf(v0, v1); w.y = pkbf(v2, v3);
        *(uint2*)&epi[e*136 + m] = w;
      }
    }
    __syncthreads();
    const int e2 = t >> 1, mc = (t & 1) * 64;   // e2 0..127, mc 0/64
    const int h = h0 + (e2 >> 6), d = e2 & 63;
    const int sb = (s0m >> 6) + (mc >> 6);
    u16* dst = Vt64 + (((size_t)(b * NH + h) * 32 + sb) * 64 + d) * 64;
    #pragma unroll
    for (int i = 0; i < 8; ++i)
      *(uint4*)(dst + i*8) = *(const uint4*)&epi[e2*136 + mc + i*8];
  } else {
    // stage C[m][e] (stride 136); coalesced rows -> Qw/Kw[bh][s][dh]
    #pragma unroll
    for (int m2 = 0; m2 < 4; ++m2) {
      #pragma unroll
      for (int ni = 0; ni < 4; ++ni) {
        int e = wc*64 + ni*16 + fr;
        float bv = bias[n0 + e];
        #pragma unroll
        for (int r = 0; r < 4; ++r) {
          float v = acc[m2][ni][r] + bv;
          if (z == 0) v *= QSCALE;
          v = fmaxf(v, 0.f);
          epi[(wr*64 + m2*16 + fg*4 + r)*136 + e] = bfbits(v);
        }
      }
    }
    __syncthreads();
    const int mrow = t >> 1, hf = t & 1;
    u16* dst = ((z == 0) ? Qw : Kw) +
               (((size_t)(b * NH + h0 + hf)) * S_LEN + s0m + mrow) * DHD;
    #pragma unroll
    for (int i = 0; i < 8; ++i)
      *(uint4*)(dst + i*8) = *(const uint4*)&epi[mrow*136 + hf*64 + i*8];
  }
}

// longest-first block table: (qb, chunk) for the 34 blocks per bh
static __device__ const uint8_t QBT[34] = {4,5,6,7,8,9,9,10,10,11,11,12,12,13,13,14,14,14,15,15,15,
                                           3,8,13, 2,7,12, 1,6,11, 0,5,10,15};
static __device__ const uint8_t CKT[34] = {0,0,0,0,0,0,1,0,1,0,1,0,1,0,1,0,1,2,0,1,2,
                                           0,1,2, 0,1,2, 0,1,2, 0,1,2,3};

// ---------------------------------------------------------------------------
// Flash attention, 2 steps per barrier: 4 waves/block, FOUR 64-row K/V LDS
// buffers (64 KB) staged via global_load_lds one full iteration ahead ->
// barrier count halved and stage drains fully hidden (~1400cy compute between
// issue and drain). Unnormalized p=exp2(s); split-K chunks <=10 steps (all
// chunk step-counts are even, so no odd tail).
// ---------------------------------------------------------------------------
__launch_bounds__(256, 2)
__global__ void attn_kernel(const u16* __restrict__ Qw, const u16* __restrict__ Kw,
                            const u16* __restrict__ Vt64, u16* __restrict__ Opart,
                            float* __restrict__ lbuf, float* __restrict__ out) {
  __shared__ u16 KLDS[4][4096];
  __shared__ u16 VLDS[4][4096];
  const int t = threadIdx.x;
  const int lane = t & 63;
  const int wid = t >> 6;
  const int lam = lane & 31;
  const int hi = lane >> 5;
  const int h8 = hi << 3, h4 = hi << 2;
  const int bid = blockIdx.x;
  const int bh = bid & 15;              // xcd = bid&7
  const int u = bid >> 4;               // 0..33
  const int qb = QBT[u], chunk = CKT[u];
  const int steps_total = (qb + 1) * 2;
  const int sc0 = chunk * 10;
  const int sc1e = sc0 + 10;
  const int sc1 = (sc1e < steps_total) ? sc1e : steps_total;
  const int t32 = qb * 4 + wid;
  const int q0 = qb * 128 + wid * 32;

  const u16* __restrict__ Qh = Qw + (size_t)bh * S_LEN * DHD;
  const u16* __restrict__ Kh = Kw + (size_t)bh * S_LEN * DHD;
  const u16* __restrict__ V64 = Vt64 + (size_t)bh * 32 * 64 * 64;

  bf16x8 qf[4];
  #pragma unroll
  for (int c = 0; c < 4; ++c)
    qf[c] = *(const bf16x8*)(Qh + (size_t)(q0 + lam) * DHD + c*16 + h8);

  const int lrow = lane >> 3;           // 0..7 within chunk
  const int lblk = lane & 7;
  auto stage = [&](int bf, int s) {
    #pragma unroll
    for (int i = 0; i < 2; ++i) {       // K,V: 8 chunks of 1KB each, 2 per wave
      int c = wid * 2 + i;
      int r = c * 8 + lrow;             // 0..63
      int sw = (lblk ^ (r & 7)) << 3;   // XOR-pre-swizzled source block (u16)
      gload16(Kh + (size_t)(s * 64 + r) * 64 + sw, &KLDS[bf][c * 512]);
      gload16(V64 + ((size_t)s * 64 + r) * 64 + sw, &VLDS[bf][c * 512]);
    }
  };

  f32x16 o0 = {}, o1 = {};
  float lsum = 0.f;

  auto softpack = [&](const f32x16& sc, bool msk, bf16x8& pb0v, bf16x8& pb1v) {
    float p[16];
    #pragma unroll
    for (int r = 0; r < 16; ++r) {
      float ev = __builtin_amdgcn_exp2f(sc[r]);
      int kc = (r & 3) + ((r >> 2) << 3) + h4;
      if (msk && kc > lam) ev = 0.f;
      p[r] = ev;
      lsum += ev;
    }
    uint32_t X0 = pkbf(p[0], p[1]),  X1 = pkbf(p[2], p[3]);
    uint32_t X2 = pkbf(p[4], p[5]),  X3 = pkbf(p[6], p[7]);
    uint32_t X4 = pkbf(p[8], p[9]),  X5 = pkbf(p[10], p[11]);
    uint32_t X6 = pkbf(p[12], p[13]), X7 = pkbf(p[14], p[15]);
    asm("v_permlane32_swap_b32 %0, %1" : "+v"(X0), "+v"(X2));
    asm("v_permlane32_swap_b32 %0, %1" : "+v"(X1), "+v"(X3));
    asm("v_permlane32_swap_b32 %0, %1" : "+v"(X4), "+v"(X6));
    asm("v_permlane32_swap_b32 %0, %1" : "+v"(X5), "+v"(X7));
    union U8 { uint32_t u[4]; bf16x8 v; };
    U8 a, bU;
    a.u[0] = X0; a.u[1] = X1; a.u[2] = X2; a.u[3] = X3;
    bU.u[0] = X4; bU.u[1] = X5; bU.u[2] = X6; bU.u[3] = X7;
    pb0v = a.v; pb1v = bU.v;
  };

  // one 64-row KV step from buffer `buf`
  auto do_step = [&](int s, int buf) {
    const int d2 = t32 - 2 * s;         // A computes if >=0 (diag ==0); B if >=1 (diag ==1)
    bf16x8 a0, a1, b0v, b1v;
    f32x16 sA = {}, sB = {};
    if (d2 >= 0) {
      bf16x8 kA[4];
      #pragma unroll
      for (int c = 0; c < 4; ++c) {
        int r = lam, e = ((2*c + hi) ^ (r & 7)) * 8;
        kA[c] = *(const bf16x8*)&KLDS[buf][r*64 + e];
      }
      __builtin_amdgcn_s_setprio(1);
      #pragma unroll
      for (int c = 0; c < 4; ++c)
        sA = __builtin_amdgcn_mfma_f32_32x32x16_bf16(kA[c], qf[c], sA, 0, 0, 0);
      __builtin_amdgcn_s_setprio(0);
    }
    if (d2 >= 1) {
      bf16x8 kB[4];
      #pragma unroll
      for (int c = 0; c < 4; ++c) {
        int r = 32 + lam, e = ((2*c + hi) ^ (r & 7)) * 8;
        kB[c] = *(const bf16x8*)&KLDS[buf][r*64 + e];
      }
      __builtin_amdgcn_s_setprio(1);
      #pragma unroll
      for (int c = 0; c < 4; ++c)
        sB = __builtin_amdgcn_mfma_f32_32x32x16_bf16(kB[c], qf[c], sB, 0, 0, 0);
      __builtin_amdgcn_s_setprio(0);
    }
    if (d2 >= 0) softpack(sA, d2 == 0, a0, a1);
    if (d2 >= 1) softpack(sB, d2 == 1, b0v, b1v);
    if (d2 >= 0) {
      bf16x8 v0[2], v1[2];
      #pragma unroll
      for (int c2 = 0; c2 < 2; ++c2) {
        int r0 = lam,      e0 = ((2*c2 + hi) ^ (r0 & 7)) * 8;
        int r1 = 32 + lam, e1 = ((2*c2 + hi) ^ (r1 & 7)) * 8;
        v0[c2] = *(const bf16x8*)&VLDS[buf][r0*64 + e0];
        v1[c2] = *(const bf16x8*)&VLDS[buf][r1*64 + e1];
      }
      __builtin_amdgcn_s_setprio(1);
      o0 = __builtin_amdgcn_mfma_f32_32x32x16_bf16(v0[0], a0, o0, 0, 0, 0);
      o0 = __builtin_amdgcn_mfma_f32_32x32x16_bf16(v0[1], a1, o0, 0, 0, 0);
      o1 = __builtin_amdgcn_mfma_f32_32x32x16_bf16(v1[0], a0, o1, 0, 0, 0);
      o1 = __builtin_amdgcn_mfma_f32_32x32x16_bf16(v1[1], a1, o1, 0, 0, 0);
      __builtin_amdgcn_s_setprio(0);
    }
    if (d2 >= 1) {
      bf16x8 v0[2], v1[2];
      #pragma unroll
      for (int c2 = 0; c2 < 2; ++c2) {
        int r0 = lam,      e0 = ((4 + 2*c2 + hi) ^ (r0 & 7)) * 8;
        int r1 = 32 + lam, e1 = ((4 + 2*c2 + hi) ^ (r1 & 7)) * 8;
        v0[c2] = *(const bf16x8*)&VLDS[buf][r0*64 + e0];
        v1[c2] = *(const bf16x8*)&VLDS[buf][r1*64 + e1];
      }
      __builtin_amdgcn_s_setprio(1);
      o0 = __builtin_amdgcn_mfma_f32_32x32x16_bf16(v0[0], b0v, o0, 0, 0, 0);
      o0 = __builtin_amdgcn_mfma_f32_32x32x16_bf16(v0[1], b1v, o0, 0, 0, 0);
      o1 = __builtin_amdgcn_mfma_f32_32x32x16_bf16(v1[0], b0v, o1, 0, 0, 0);
      o1 = __builtin_amdgcn_mfma_f32_32x32x16_bf16(v1[1], b1v, o1, 0, 0, 0);
      __builtin_amdgcn_s_setprio(0);
    }
  };

  // 2 steps per barrier; stages issued one full iteration ahead.
  // All chunk step-counts are even, so no odd tail.
  stage(0, sc0);
  stage(1, sc0 + 1);
  int ib = 0;
  for (int s = sc0; s < sc1; s += 2) {
    __syncthreads();                    // drains stages issued LAST iteration
    if (s + 2 < sc1) {
      stage((ib + 2) & 3, s + 2);
      stage((ib + 3) & 3, s + 3);
    }
    do_step(s, ib);
    do_step(s + 1, (ib + 1) & 3);
    ib = (ib + 2) & 3;
  }

  float l = lsum + __shfl_xor(lsum, 32);

  if (qb <= 4) {
    const int b = bh >> 3, hh = bh & 7;
    const float inv = 1.0f / l;
    float* orow = out + (((size_t)(hh * NB + b)) * S_LEN + (q0 + lam)) * DHD;
    #pragma unroll
    for (int r = 0; r < 16; ++r) {
      int d = (r & 3) + ((r >> 2) << 3) + h4;
      orow[d] = o0[r] * inv;
      orow[d + 32] = o1[r] * inv;
    }
  } else {
    const int slot = slot_of(bh, t32, chunk);
    uint32_t w[16] __attribute__((aligned(16)));
    #pragma unroll
    for (int m = 0; m < 8; ++m) {
      w[m]     = pkbf(o0[2*m], o0[2*m+1]);
      w[8 + m] = pkbf(o1[2*m], o1[2*m+1]);
    }
    u16* op = Opart + (size_t)slot * 2048 + (size_t)lane * 32;
    #pragma unroll
    for (int i = 0; i < 4; ++i)
      *(uint4*)(op + i*8) = *(const uint4*)&w[i*4];
    if (lane < 32) lbuf[slot * 32 + lane] = l;
  }
}

// ---------------------------------------------------------------------------
// Combine split-K partials for tiles with qb>=5 (t32 20..63): plain sums.
// ---------------------------------------------------------------------------
__launch_bounds__(256)
__global__ void reduce_kernel(const u16* __restrict__ Opart,
                              const float* __restrict__ lbuf,
                              float* __restrict__ out) {
  const int t = threadIdx.x;
  const int unit = blockIdx.x * 4 + (t >> 6);   // 0..703
  const int bh = unit & 15;
  const int ti = 20 + (unit >> 4);              // t32 20..63
  const int qb = ti >> 2;
  const int nc = (2 * (qb + 1) + 9) / 10;       // 2..4
  const int lane = t & 63;
  const int lam = lane & 31;
  const int h4 = (lane >> 5) << 2;
  const int slot0 = slot_of(bh, ti, 0);

  float O[32];
  #pragma unroll
  for (int i = 0; i < 32; ++i) O[i] = 0.f;
  float L = 0.f;

  for (int c = 0; c < nc; ++c) {
    const u16* op = Opart + (size_t)(slot0 + c) * 2048 + (size_t)lane * 32;
    L += lbuf[(slot0 + c) * 32 + lam];
    #pragma unroll
    for (int i = 0; i < 4; ++i) {
      uint4 v = *(const uint4*)(op + i*8);
      uint32_t a[4] = {v.x, v.y, v.z, v.w};
      #pragma unroll
      for (int jj = 0; jj < 4; ++jj) {
        O[i*8 + 2*jj]     += bits2f((u16)(a[jj] & 0xFFFFu));
        O[i*8 + 2*jj + 1] += bits2f((u16)(a[jj] >> 16));
      }
    }
  }

  const int b = bh >> 3, hh = bh & 7;
  const float inv = 1.0f / L;
  float* orow = out + (((size_t)(hh * NB + b)) * S_LEN + (ti*32 + lam)) * DHD;
  #pragma unroll
  for (int r = 0; r < 16; ++r) {
    int d = (r & 3) + ((r >> 2) << 3) + h4;
    orow[d] = O[r] * inv;
    orow[d + 32] = O[16 + r] * inv;
  }
}

extern "C" void kernel_launch(void* const* d_in, const int* in_sizes, int n_in,
                              void* d_out, int out_size, void* d_ws, size_t ws_size,
                              hipStream_t stream) {
  const float* q = (const float*)d_in[0];
  const float* k = (const float*)d_in[1];
  const float* v = (const float*)d_in[2];
  const float* W = (const float*)d_in[3];
  const float* b = (const float*)d_in[4];

  const size_t elems = (size_t)NB * NH * S_LEN * DHD;  // 2,097,152
  u16* Qw = (u16*)d_ws;
  u16* Kw = Qw + elems;
  u16* Vt64 = Kw + elems;
  u16* Opart = Vt64 + elems;                           // 1856 slots * 4 KiB = 7.25 MiB
  float* lbuf = (float*)(Opart + (size_t)1856 * 2048); // 232 KiB

  proj_kernel<<<dim3(384), dim3(256), 0, stream>>>(q, k, v, W, b, Qw, Kw, Vt64);

  attn_kernel<<<dim3(544), dim3(256), 0, stream>>>(Qw, Kw, Vt64, Opart, lbuf, (float*)d_out);

  reduce_kernel<<<dim3(176), dim3(256), 0, stream>>>(Opart, lbuf, (float*)d_out);
}